// Round 6
// baseline (2572.955 us; speedup 1.0000x reference)
//
#include <hip/hip_runtime.h>
#include <math.h>

// Problem constants (B,T,N,D) = (2,64,512,256)
#define B_ 2
#define T_ 64
#define N_ 512
#define D_ 256
#define M_ (B_*T_*N_)            // 65536 rows for the GEMMs
#define PLANE ((size_t)M_*D_)    // 16777216 elements per output plane

typedef unsigned short u16;
typedef __attribute__((ext_vector_type(8))) short bf16x8;
typedef __attribute__((ext_vector_type(4))) float f32x4;

__device__ __forceinline__ u16 f2bf(float f) {
  union { float f; unsigned u; } cv; cv.f = f;
  unsigned u = cv.u;
  return (u16)((u + 0x7FFFu + ((u >> 16) & 1u)) >> 16);   // RNE
}
__device__ __forceinline__ float bf2f(u16 h) {
  union { unsigned u; float f; } cv; cv.u = ((unsigned)h) << 16;
  return cv.f;
}

// ---------------------------------------------------------------------------
// A init: col-major float2 A[c*256+r] = raw[r][c]
// ---------------------------------------------------------------------------
__global__ __launch_bounds__(1024) void qr_init_kernel(
    const float* __restrict__ ure_raw, const float* __restrict__ uim_raw,
    float2* __restrict__ A)
{
  int i = blockIdx.x * 1024 + threadIdx.x;   // 64 blocks
  int c = i >> 8, r = i & 255;
  A[i] = make_float2(ure_raw[r*D_ + c], uim_raw[r*D_ + c]);
}

// ---------------------------------------------------------------------------
// Panel factorization (zgeqr2 on cols j0..j0+31, rows j0..255), LAPACK
// convention, fp32. ONE WAVE (64 threads): whole panel in registers
// (col[32][4] float2 = 256 VGPRs), all sync intra-wave (free), zero LDS.
// Runtime column index jl handled by unrolled uniform `lc==jl` branches so
// register indexing stays static (no scratch). Chunk guard m<MCH skips
// all-zero 64-row chunks for later panels.
// ---------------------------------------------------------------------------
__global__ __launch_bounds__(64, 1) void qr_panel_kernel(
    float2* __restrict__ A, float2* __restrict__ tau, int j0)
{
  const int lane = threadIdx.x;
  const int R = 256 - j0;
  const int MCH = (R + 63) >> 6;
  float2 col[32][4];
  #pragma unroll
  for (int lc = 0; lc < 32; ++lc) {
    #pragma unroll
    for (int m = 0; m < 4; ++m) {
      col[lc][m] = make_float2(0.f, 0.f);
      int rr = m*64 + lane;
      if (m < MCH && rr < R) col[lc][m] = A[(size_t)(j0+lc)*D_ + j0 + rr];
    }
  }

  #pragma unroll 1
  for (int jl = 0; jl < 32; ++jl) {
    // extract column jl (static indices, uniform branches)
    float2 d0 = make_float2(0.f,0.f), d1 = d0, d2 = d0, d3 = d0;
    #pragma unroll
    for (int lc = 0; lc < 32; ++lc)
      if (lc == jl) { d0 = col[lc][0]; d1 = col[lc][1];
                      d2 = col[lc][2]; d3 = col[lc][3]; }
    // norm below diagonal (rows >= R are zero by construction)
    float part = (lane > jl) ? (d0.x*d0.x + d0.y*d0.y) : 0.f;
    if (1 < MCH) part += d1.x*d1.x + d1.y*d1.y;
    if (2 < MCH) part += d2.x*d2.x + d2.y*d2.y;
    if (3 < MCH) part += d3.x*d3.x + d3.y*d3.y;
    #pragma unroll
    for (int s = 32; s; s >>= 1) part += __shfl_xor(part, s);
    float ar = __shfl(d0.x, jl), ai = __shfl(d0.y, jl);
    float taur, taui, sclr, scli, beta;
    if (part == 0.f && ai == 0.f) {
      taur = taui = sclr = scli = 0.f; beta = ar;     // H = I
    } else {
      float nrm = sqrtf(ar*ar + ai*ai + part);
      beta = (ar >= 0.f) ? -nrm : nrm;                // -SIGN(nrm, Re(alpha))
      taur = (beta - ar)/beta; taui = -ai/beta;
      float dr = ar - beta, di = ai, dn = dr*dr + di*di;
      sclr = dr/dn; scli = -di/dn;                    // 1/(alpha-beta)
    }
    if (lane == 0) tau[j0 + jl] = make_float2(taur, taui);
    // form v (v[<jl]=0, v[jl]=1, scaled below)
    float2 v0 = make_float2(d0.x*sclr - d0.y*scli, d0.x*scli + d0.y*sclr);
    if (lane == jl) v0 = make_float2(1.f, 0.f);
    if (lane <  jl) v0 = make_float2(0.f, 0.f);
    float2 v1 = make_float2(d1.x*sclr - d1.y*scli, d1.x*scli + d1.y*sclr);
    float2 v2 = make_float2(d2.x*sclr - d2.y*scli, d2.x*scli + d2.y*sclr);
    float2 v3 = make_float2(d3.x*sclr - d3.y*scli, d3.x*scli + d3.y*sclr);
    // writeback column jl: rows<jl keep R part, diag=beta, below=v
    #pragma unroll
    for (int lc = 0; lc < 32; ++lc)
      if (lc == jl) {
        float2 w0 = v0;
        if (lane == jl) w0 = make_float2(beta, 0.f);
        if (lane <  jl) w0 = col[lc][0];
        col[lc][0] = w0; col[lc][1] = v1; col[lc][2] = v2; col[lc][3] = v3;
      }
    // trailing update within panel
    #pragma unroll
    for (int lc = 0; lc < 32; ++lc) {
      if (lc > jl) {
        float wr, wi;
        { float2 a = col[lc][0];
          wr = v0.x*a.x + v0.y*a.y; wi = v0.x*a.y - v0.y*a.x; }
        if (1 < MCH) { float2 a = col[lc][1];
          wr += v1.x*a.x + v1.y*a.y; wi += v1.x*a.y - v1.y*a.x; }
        if (2 < MCH) { float2 a = col[lc][2];
          wr += v2.x*a.x + v2.y*a.y; wi += v2.x*a.y - v2.y*a.x; }
        if (3 < MCH) { float2 a = col[lc][3];
          wr += v3.x*a.x + v3.y*a.y; wi += v3.x*a.y - v3.y*a.x; }
        #pragma unroll
        for (int s = 32; s; s >>= 1) { wr += __shfl_xor(wr, s);
                                       wi += __shfl_xor(wi, s); }
        float fr = taur*wr + taui*wi;                 // f = conj(tau)*w
        float fi = taur*wi - taui*wr;
        { col[lc][0].x -= fr*v0.x - fi*v0.y; col[lc][0].y -= fr*v0.y + fi*v0.x; }
        if (1 < MCH) { col[lc][1].x -= fr*v1.x - fi*v1.y;
                       col[lc][1].y -= fr*v1.y + fi*v1.x; }
        if (2 < MCH) { col[lc][2].x -= fr*v2.x - fi*v2.y;
                       col[lc][2].y -= fr*v2.y + fi*v2.x; }
        if (3 < MCH) { col[lc][3].x -= fr*v3.x - fi*v3.y;
                       col[lc][3].y -= fr*v3.y + fi*v3.x; }
      }
    }
  }

  #pragma unroll
  for (int lc = 0; lc < 32; ++lc) {
    #pragma unroll
    for (int m = 0; m < 4; ++m) {
      int rr = m*64 + lane;
      if (m < MCH && rr < R) A[(size_t)(j0+lc)*D_ + j0 + rr] = col[lc][m];
    }
  }
}

// ---------------------------------------------------------------------------
// Apply panel j0's 32 reflectors to a 32-column trailing tile (registers).
// blockIdx.x selects the tile; v streamed from L2 per reflector per wave.
// Chunk guard m<MCH skips all-zero chunks.
// ---------------------------------------------------------------------------
__global__ __launch_bounds__(256, 1) void qr_apply_kernel(
    float2* __restrict__ A, const float2* __restrict__ tau, int j0)
{
  const int tid = threadIdx.x, lane = tid & 63, w = tid >> 6;
  const int R = 256 - j0;
  const int MCH = (R + 63) >> 6;
  const int c0 = j0 + 32 + blockIdx.x * 32;
  float2 col[8][4];
  #pragma unroll
  for (int lc = 0; lc < 8; ++lc) {
    int cg = c0 + lc*4 + w;
    #pragma unroll
    for (int m = 0; m < 4; ++m) {
      col[lc][m] = make_float2(0.f, 0.f);
      int rr = m*64 + lane;
      if (m < MCH && rr < R) col[lc][m] = A[(size_t)cg*D_ + j0 + rr];
    }
  }
  #pragma unroll 1
  for (int jl = 0; jl < 32; ++jl) {
    float2 tt = tau[j0 + jl];
    float2 v[4];
    #pragma unroll
    for (int m = 0; m < 4; ++m) {
      v[m] = make_float2(0.f, 0.f);
      int rr = m*64 + lane;
      if (m < MCH && rr < R) {
        float2 raw = A[(size_t)(j0+jl)*D_ + j0 + rr];
        v[m] = (rr > jl) ? raw
             : ((rr == jl) ? make_float2(1.f, 0.f) : make_float2(0.f, 0.f));
      }
    }
    float wr[8], wi[8];
    #pragma unroll
    for (int lc = 0; lc < 8; ++lc) {
      wr[lc] = 0.f; wi[lc] = 0.f;
      #pragma unroll
      for (int m = 0; m < 4; ++m) {
        if (m < MCH) {
          float2 a = col[lc][m];
          wr[lc] += v[m].x*a.x + v[m].y*a.y;
          wi[lc] += v[m].x*a.y - v[m].y*a.x;
        }
      }
    }
    #pragma unroll
    for (int lc = 0; lc < 8; ++lc) {
      #pragma unroll
      for (int s = 32; s; s >>= 1) { wr[lc] += __shfl_xor(wr[lc], s);
                                     wi[lc] += __shfl_xor(wi[lc], s); }
    }
    #pragma unroll
    for (int lc = 0; lc < 8; ++lc) {
      float fr = tt.x*wr[lc] + tt.y*wi[lc];
      float fi = tt.x*wi[lc] - tt.y*wr[lc];
      #pragma unroll
      for (int m = 0; m < 4; ++m) {
        if (m < MCH) {
          col[lc][m].x -= fr*v[m].x - fi*v[m].y;
          col[lc][m].y -= fr*v[m].y + fi*v[m].x;
        }
      }
    }
  }
  #pragma unroll
  for (int lc = 0; lc < 8; ++lc) {
    int cg = c0 + lc*4 + w;
    #pragma unroll
    for (int m = 0; m < 4; ++m) {
      int rr = m*64 + lane;
      if (m < MCH && rr < R) A[(size_t)cg*D_ + j0 + rr] = col[lc][m];
    }
  }
}

// ---------------------------------------------------------------------------
// zung2r: column c of Q = H_0(...H_c(e_c)); one wave per column, branch-free
// body, v-prefetch (round-5 version, measured 134 us).
// Epilogue writes bf16 B^T matrices for both GEMMs.
// ---------------------------------------------------------------------------
__global__ __launch_bounds__(256, 1) void qr_bwd_kernel(
    const float2* __restrict__ A, const float2* __restrict__ tau,
    u16* __restrict__ Benc, u16* __restrict__ Bdec)
{
  const int lane = threadIdx.x & 63;
  const int w = threadIdx.x >> 6;
  const int c = blockIdx.x * 4 + w;          // column 0..255
  __shared__ float2 stau[256];
  if (threadIdx.x < 256) stau[threadIdx.x] = tau[threadIdx.x];
  __syncthreads();

  float2 q[4];
  #pragma unroll
  for (int m = 0; m < 4; ++m) {
    q[m] = make_float2(0.f, 0.f);
    if (m*64 + lane == c) q[m].x = 1.f;      // q = e_c
  }
  float2 araw[4];                            // prefetched raw column i
  #pragma unroll
  for (int m = 0; m < 4; ++m) araw[m] = A[(size_t)c*D_ + m*64 + lane];

  for (int i = c; i >= 0; --i) {
    float2 tt = stau[i];
    float2 v[4];
    #pragma unroll
    for (int m = 0; m < 4; ++m) {
      int r = m*64 + lane;
      v[m] = (r > i) ? araw[m] : ((r == i) ? make_float2(1.f, 0.f)
                                           : make_float2(0.f, 0.f));
    }
    int inext = (i > 0) ? i - 1 : 0;
    #pragma unroll
    for (int m = 0; m < 4; ++m) araw[m] = A[(size_t)inext*D_ + m*64 + lane];

    float wr = 0.f, wi = 0.f;
    #pragma unroll
    for (int m = 0; m < 4; ++m) {
      wr += v[m].x*q[m].x + v[m].y*q[m].y;   // w += conj(v)*q
      wi += v[m].x*q[m].y - v[m].y*q[m].x;
    }
    #pragma unroll
    for (int s = 32; s; s >>= 1) { wr += __shfl_xor(wr, s); wi += __shfl_xor(wi, s); }
    float fr = tt.x*wr - tt.y*wi;            // f = tau*w  (0 when tau==0)
    float fi = tt.x*wi + tt.y*wr;
    #pragma unroll
    for (int m = 0; m < 4; ++m) {
      q[m].x -= fr*v[m].x - fi*v[m].y;
      q[m].y -= fr*v[m].y + fi*v[m].x;
    }
  }

  #pragma unroll
  for (int m = 0; m < 4; ++m) {
    int r = m*64 + lane;
    u16 qre = f2bf(q[m].x), qim = f2bf(q[m].y), qimn = f2bf(-q[m].y);
    Benc[(size_t)c*D_ + r]              = qre;
    Benc[(size_t)(c+256)*D_ + r]        = qim;
    Bdec[(size_t)c*512 + r]             = qre;
    Bdec[(size_t)c*512 + 256 + r]       = qimn;
    Bdec[(size_t)(c+256)*512 + r]       = qim;
    Bdec[(size_t)(c+256)*512 + 256 + r] = qre;
  }
}

// ---------------------------------------------------------------------------
// Per-(b,t,d) coefficients (tables; avoids 270M transcendentals in scan).
// ---------------------------------------------------------------------------
__global__ __launch_bounds__(256) void coef_kernel(
  const float* __restrict__ dt, const float* __restrict__ lam_re, const float* __restrict__ lam_im,
  const float* __restrict__ noise_raw,
  float* __restrict__ c_dre, float* __restrict__ c_dim, float* __restrict__ c_fre,
  float* __restrict__ c_fim, float* __restrict__ c_ns)
{
  int bt = blockIdx.x; int d = threadIdx.x;
  float dtv = dt[bt];
  float lr = lam_re[d], li = lam_im[d];
  float lam_r = fmaxf(-log1pf(expf(-lr)), -0.3f);
  float ar = dtv*lam_r, ai = dtv*li;
  float er = expf(ar);
  float dre = er*cosf(ai), dim_ = er*sinf(ai);
  float t = lam_r + 1e-12f;
  float sgn = (t > 0.f) ? 1.f : ((t < 0.f) ? -1.f : 0.f);
  float den_re = lam_r + 1e-8f*sgn, den_im = li;
  float nr = dre - 1.f, ni = dim_;
  float d2 = den_re*den_re + den_im*den_im;
  float fre = (nr*den_re + ni*den_im)/d2;
  float fim = (ni*den_re - nr*den_im)/d2;
  float ns = sqrtf(fmaxf(dtv,0.f)) * log1pf(expf(noise_raw[d])) * 0.01f;
  int idx = bt*D_+d;
  c_dre[idx]=dre; c_dim[idx]=dim_; c_fre[idx]=fre; c_fim[idx]=fim; c_ns[idx]=ns;
}

// ---------------------------------------------------------------------------
// bf16 MFMA GEMM, 128x128 tile, 4 waves, BK=64, 16x16x32 MFMA.
// encode_gemm reads fp32 x directly and converts during staging (xconv fused).
// LDS row stride 72 elements (144 B): 16B-aligned, 2-way banks (free).
// ---------------------------------------------------------------------------
#define LDT 72

__global__ __launch_bounds__(256) void encode_gemm(
    const float* __restrict__ x, const u16* __restrict__ Bt,
    u16* __restrict__ xer16, u16* __restrict__ xei16)
{
  __shared__ u16 sA[128*LDT];
  __shared__ u16 sB[128*LDT];
  const int tid = threadIdx.x;
  const int lane = tid & 63, w = tid >> 6;
  const int wr = w >> 1, wc = w & 1;
  const int l15 = lane & 15, l4 = lane >> 4;
  const int m0 = blockIdx.x * 128;
  const int n0 = blockIdx.y * 128;
  f32x4 acc[4][4] = {};
  for (int kb = 0; kb < 4; ++kb) {
    #pragma unroll
    for (int i = 0; i < 4; ++i) {
      int chunk = i*256 + tid;
      int row = chunk >> 3, k0 = (chunk & 7) * 8;
      const float* xs = x + (size_t)(m0+row)*D_ + kb*64 + k0;
      float4 f0 = *(const float4*)xs;
      float4 f1 = *(const float4*)(xs + 4);
      int4 va;
      va.x = (int)((unsigned)f2bf(f0.x) | ((unsigned)f2bf(f0.y) << 16));
      va.y = (int)((unsigned)f2bf(f0.z) | ((unsigned)f2bf(f0.w) << 16));
      va.z = (int)((unsigned)f2bf(f1.x) | ((unsigned)f2bf(f1.y) << 16));
      va.w = (int)((unsigned)f2bf(f1.z) | ((unsigned)f2bf(f1.w) << 16));
      int4 vb = *(const int4*)(Bt + (size_t)(n0+row)*D_ + kb*64 + k0);
      *(int4*)&sA[row*LDT + k0] = va;
      *(int4*)&sB[row*LDT + k0] = vb;
    }
    __syncthreads();
    #pragma unroll
    for (int ks = 0; ks < 2; ++ks) {
      bf16x8 af[4], bb[4];
      #pragma unroll
      for (int mf = 0; mf < 4; ++mf)
        af[mf] = *(const bf16x8*)&sA[(wr*64 + mf*16 + l15)*LDT + ks*32 + l4*8];
      #pragma unroll
      for (int nf = 0; nf < 4; ++nf)
        bb[nf] = *(const bf16x8*)&sB[(wc*64 + nf*16 + l15)*LDT + ks*32 + l4*8];
      #pragma unroll
      for (int mf = 0; mf < 4; ++mf)
        #pragma unroll
        for (int nf = 0; nf < 4; ++nf)
          acc[mf][nf] = __builtin_amdgcn_mfma_f32_16x16x32_bf16(
              af[mf], bb[nf], acc[mf][nf], 0, 0, 0);
    }
    __syncthreads();
  }
  #pragma unroll
  for (int mf = 0; mf < 4; ++mf)
    #pragma unroll
    for (int nf = 0; nf < 4; ++nf)
      #pragma unroll
      for (int r = 0; r < 4; ++r) {
        int row = m0 + wr*64 + mf*16 + l4*4 + r;
        int col = n0 + wc*64 + nf*16 + l15;
        float v = acc[mf][nf][r];
        if (col < 256) xer16[(size_t)row*D_ + col] = f2bf(v);
        else           xei16[(size_t)row*D_ + col - 256] = f2bf(-v);
      }
}

__global__ __launch_bounds__(256) void decode_gemm(
    const u16* __restrict__ hre16, const u16* __restrict__ him16,
    const u16* __restrict__ Bt, float* __restrict__ out)
{
  __shared__ u16 sA[128*LDT];
  __shared__ u16 sB[128*LDT];
  const int tid = threadIdx.x;
  const int lane = tid & 63, w = tid >> 6;
  const int wr = w >> 1, wc = w & 1;
  const int l15 = lane & 15, l4 = lane >> 4;
  const int m0 = blockIdx.x * 128;
  const int n0 = blockIdx.y * 128;
  f32x4 acc[4][4] = {};
  for (int kb = 0; kb < 8; ++kb) {
    const u16* aplane = (kb < 4) ? hre16 : him16;
    const int kk = (kb & 3) * 64;
    #pragma unroll
    for (int i = 0; i < 4; ++i) {
      int chunk = i*256 + tid;
      int row = chunk >> 3, k0 = (chunk & 7) * 8;
      int4 va = *(const int4*)(aplane + (size_t)(m0+row)*D_ + kk + k0);
      int4 vb = *(const int4*)(Bt + (size_t)(n0+row)*512 + kb*64 + k0);
      *(int4*)&sA[row*LDT + k0] = va;
      *(int4*)&sB[row*LDT + k0] = vb;
    }
    __syncthreads();
    #pragma unroll
    for (int ks = 0; ks < 2; ++ks) {
      bf16x8 af[4], bb[4];
      #pragma unroll
      for (int mf = 0; mf < 4; ++mf)
        af[mf] = *(const bf16x8*)&sA[(wr*64 + mf*16 + l15)*LDT + ks*32 + l4*8];
      #pragma unroll
      for (int nf = 0; nf < 4; ++nf)
        bb[nf] = *(const bf16x8*)&sB[(wc*64 + nf*16 + l15)*LDT + ks*32 + l4*8];
      #pragma unroll
      for (int mf = 0; mf < 4; ++mf)
        #pragma unroll
        for (int nf = 0; nf < 4; ++nf)
          acc[mf][nf] = __builtin_amdgcn_mfma_f32_16x16x32_bf16(
              af[mf], bb[nf], acc[mf][nf], 0, 0, 0);
    }
    __syncthreads();
  }
  #pragma unroll
  for (int mf = 0; mf < 4; ++mf)
    #pragma unroll
    for (int nf = 0; nf < 4; ++nf)
      #pragma unroll
      for (int r = 0; r < 4; ++r) {
        int row = m0 + wr*64 + mf*16 + l4*4 + r;
        int col = n0 + wc*64 + nf*16 + l15;
        float v = acc[mf][nf][r];
        if (col < 256) out[(size_t)row*D_ + col] = v;
        else           out[PLANE + (size_t)row*D_ + col - 256] = v;
      }
}

// ---------------------------------------------------------------------------
// Scan: reads bf16 x_enc planes + fp32 eps + coef tables (L2-resident);
// writes bf16 h planes. One block per (b,n); thread = d.
// ---------------------------------------------------------------------------
__global__ __launch_bounds__(256) void scan_kernel(
  const float* __restrict__ eps,
  const float* __restrict__ c_dre, const float* __restrict__ c_dim,
  const float* __restrict__ c_fre, const float* __restrict__ c_fim, const float* __restrict__ c_ns,
  const u16* __restrict__ xer16, const u16* __restrict__ xei16,
  u16* __restrict__ hre16, u16* __restrict__ him16)
{
  int bx = blockIdx.x;
  int b = bx >> 9, n = bx & 511;
  int d = threadIdx.x;
  float hr = 0.f, hi = 0.f;
  for (int t = 0; t < T_; ++t) {
    int bt = b*T_ + t;
    int cidx = bt*D_ + d;
    float dre = c_dre[cidx], dim_ = c_dim[cidx];
    float fre = c_fre[cidx], fim = c_fim[cidx];
    float ns  = c_ns[cidx];
    size_t idx = ((size_t)bt*N_ + n)*D_ + d;
    float xr = bf2f(xer16[idx]), xi = bf2f(xei16[idx]), ep = eps[idx];
    float br = fre*xr - fim*xi + ep*ns;
    float bi = fre*xi + fim*xr;
    float nr2 = dre*hr - dim_*hi + br;
    float ni2 = dre*hi + dim_*hr + bi;
    hr = nr2; hi = ni2;
    hre16[idx] = f2bf(hr); him16[idx] = f2bf(hi);
  }
}

// ---------------------------------------------------------------------------
extern "C" void kernel_launch(void* const* d_in, const int* in_sizes, int n_in,
                              void* d_out, int out_size, void* d_ws, size_t ws_size,
                              hipStream_t stream)
{
  const float* x         = (const float*)d_in[0];
  const float* dt        = (const float*)d_in[1];
  const float* eps       = (const float*)d_in[2];
  const float* ure_raw   = (const float*)d_in[3];
  const float* uim_raw   = (const float*)d_in[4];
  const float* lam_re    = (const float*)d_in[5];
  const float* lam_im    = (const float*)d_in[6];
  const float* noise_raw = (const float*)d_in[7];
  float* out = (float*)d_out;

  // ws layout (132 MB total):
  //   0       A float2[65536]            512 KB
  //   512K    tau float2[256]
  //   1M      Benc bf16 [512][256]       256 KB
  //   1.5M    Bdec bf16 [512][512]       512 KB
  //   2M      coef tables 5 x 64 KB      320 KB
  //   4M      hre16 bf16 [M][256] 32 MB
  //   36M     xer16 32 MB
  //   68M     xei16 32 MB
  //   100M    him16 32 MB
  char* ws = (char*)d_ws;
  float2* A    = (float2*)(ws);
  float2* tau  = (float2*)(ws + 524288);
  u16* Benc    = (u16*)(ws + (1<<20));
  u16* Bdec    = (u16*)(ws + 1572864);
  float* c_dre = (float*)(ws + (2<<20));
  float* c_dim = c_dre + B_*T_*D_;
  float* c_fre = c_dim + B_*T_*D_;
  float* c_fim = c_fre + B_*T_*D_;
  float* c_ns  = c_fim + B_*T_*D_;
  u16* hre16   = (u16*)(ws + ((size_t)4<<20));
  u16* xer16   = (u16*)(ws + ((size_t)36<<20));
  u16* xei16   = (u16*)(ws + ((size_t)68<<20));
  u16* him16   = (u16*)(ws + ((size_t)100<<20));

  qr_init_kernel<<<64, 1024, 0, stream>>>(ure_raw, uim_raw, A);
  for (int p = 0; p < 8; ++p) {
    qr_panel_kernel<<<1, 64, 0, stream>>>(A, tau, 32*p);
    int nb = 7 - p;
    if (nb > 0) qr_apply_kernel<<<nb, 256, 0, stream>>>(A, tau, 32*p);
  }
  qr_bwd_kernel<<<64, 256, 0, stream>>>(A, tau, Benc, Bdec);
  coef_kernel<<<B_*T_, 256, 0, stream>>>(dt, lam_re, lam_im, noise_raw,
                                         c_dre, c_dim, c_fre, c_fim, c_ns);
  encode_gemm<<<dim3(M_/128, 4), 256, 0, stream>>>(x, Benc, xer16, xei16);
  scan_kernel<<<B_*N_, 256, 0, stream>>>(eps, c_dre, c_dim, c_fre, c_fim, c_ns,
                                         xer16, xei16, hre16, him16);
  decode_gemm<<<dim3(M_/128, 4), 256, 0, stream>>>(hre16, him16, Bdec, out);
}

// Round 7
// 1493.739 us; speedup vs baseline: 1.7225x; 1.7225x over previous
//
#include <hip/hip_runtime.h>
#include <math.h>

// Problem constants (B,T,N,D) = (2,64,512,256)
#define B_ 2
#define T_ 64
#define N_ 512
#define D_ 256
#define M_ (B_*T_*N_)            // 65536 rows for the GEMMs
#define PLANE ((size_t)M_*D_)    // 16777216 elements per output plane

typedef unsigned short u16;
typedef __attribute__((ext_vector_type(8))) short bf16x8;
typedef __attribute__((ext_vector_type(4))) float f32x4;

__device__ __forceinline__ u16 f2bf(float f) {
  union { float f; unsigned u; } cv; cv.f = f;
  unsigned u = cv.u;
  return (u16)((u + 0x7FFFu + ((u >> 16) & 1u)) >> 16);   // RNE
}
__device__ __forceinline__ float bf2f(u16 h) {
  union { unsigned u; float f; } cv; cv.u = ((unsigned)h) << 16;
  return cv.f;
}

// ---------------------------------------------------------------------------
// A init: col-major float2 A[c*256+r] = raw[r][c]
// ---------------------------------------------------------------------------
__global__ __launch_bounds__(1024) void qr_init_kernel(
    const float* __restrict__ ure_raw, const float* __restrict__ uim_raw,
    float2* __restrict__ A)
{
  int i = blockIdx.x * 1024 + threadIdx.x;   // 64 blocks
  int c = i >> 8, r = i & 255;
  A[i] = make_float2(ure_raw[r*D_ + c], uim_raw[r*D_ + c]);
}

// ---------------------------------------------------------------------------
// Panel factorization (zgeqr2 on cols j0..j0+31), 4 waves, trailing columns
// in registers with ONLY compile-time indices. The pivot column flows through
// LDS (snext[2][256], parity double-buffer): reflector jl's update phase has
// the owner wave of column jl+1 (uniform `cl==jl+1`) store its updated column;
// reflector jl+1 reads its pivot from LDS (dynamic index free there), every
// wave redundantly computes norm/tau (no broadcast), wave 3 writes the final
// pivot column to A. One __syncthreads per reflector. No scratch (rule #20).
// ---------------------------------------------------------------------------
__global__ __launch_bounds__(256, 1) void qr_panel_kernel(
    float2* __restrict__ A, float2* __restrict__ tau, int j0)
{
  const int tid = threadIdx.x, lane = tid & 63, w = tid >> 6;
  const int R = 256 - j0;
  const int MCH = (R + 63) >> 6;
  __shared__ float2 snext[2][256];
  float2 col[8][4];

  #pragma unroll
  for (int lc = 0; lc < 8; ++lc) {
    int cg = j0 + lc*4 + w;
    #pragma unroll
    for (int m = 0; m < 4; ++m) {
      int rr = m*64 + lane;
      col[lc][m] = make_float2(0.f, 0.f);
      if (m < MCH && rr < R) col[lc][m] = A[(size_t)cg*D_ + j0 + rr];
    }
  }
  if (w == 0) {
    #pragma unroll
    for (int m = 0; m < 4; ++m) snext[0][m*64 + lane] = col[0][m];
  }
  __syncthreads();

  #pragma unroll 1
  for (int jl = 0; jl < 32; ++jl) {
    const int cur = jl & 1, nxt = cur ^ 1;
    // ---- pivot column from LDS; norm+scalars redundantly per wave ----
    float2 p[4];
    #pragma unroll
    for (int m = 0; m < 4; ++m) p[m] = snext[cur][m*64 + lane];
    float part = (lane > jl) ? (p[0].x*p[0].x + p[0].y*p[0].y) : 0.f;
    if (1 < MCH) part += p[1].x*p[1].x + p[1].y*p[1].y;
    if (2 < MCH) part += p[2].x*p[2].x + p[2].y*p[2].y;
    if (3 < MCH) part += p[3].x*p[3].x + p[3].y*p[3].y;
    #pragma unroll
    for (int s = 32; s; s >>= 1) part += __shfl_xor(part, s);
    float ar = __shfl(p[0].x, jl), ai = __shfl(p[0].y, jl);
    float taur, taui, sclr, scli, beta;
    if (part == 0.f && ai == 0.f) {
      taur = taui = sclr = scli = 0.f; beta = ar;      // H = I
    } else {
      float nrm = sqrtf(ar*ar + ai*ai + part);
      beta = (ar >= 0.f) ? -nrm : nrm;                 // -SIGN(nrm, Re(alpha))
      taur = (beta - ar)/beta; taui = -ai/beta;
      float dr = ar - beta, di = ai, dn = dr*dr + di*di;
      sclr = dr/dn; scli = -di/dn;                     // 1/(alpha-beta)
    }
    if (w == 3 && lane == 0) tau[j0 + jl] = make_float2(taur, taui);
    // ---- v in registers (per wave) ----
    float2 v[4];
    {
      float2 t0 = make_float2(p[0].x*sclr - p[0].y*scli,
                              p[0].x*scli + p[0].y*sclr);
      v[0] = (lane > jl) ? t0 : ((lane == jl) ? make_float2(1.f, 0.f)
                                              : make_float2(0.f, 0.f));
    }
    #pragma unroll
    for (int m = 1; m < 4; ++m)
      v[m] = make_float2(p[m].x*sclr - p[m].y*scli, p[m].x*scli + p[m].y*sclr);
    // ---- final pivot column -> A (wave 3; data from LDS+scalars only) ----
    if (w == 3) {
      #pragma unroll
      for (int m = 0; m < 4; ++m) {
        int rr = m*64 + lane;
        float2 o = v[m];
        if (m == 0) {
          if (lane < jl)       o = p[0];
          else if (lane == jl) o = make_float2(beta, 0.f);
        }
        if (m < MCH && rr < R) A[(size_t)(j0+jl)*D_ + j0 + rr] = o;
      }
    }
    // ---- trailing update (registers, static lc) ----
    #pragma unroll
    for (int lc = 0; lc < 8; ++lc) {
      int cl = lc*4 + w;
      if (cl > jl) {
        float wr, wi;
        { float2 a = col[lc][0];
          wr = v[0].x*a.x + v[0].y*a.y; wi = v[0].x*a.y - v[0].y*a.x; }
        if (1 < MCH) { float2 a = col[lc][1];
          wr += v[1].x*a.x + v[1].y*a.y; wi += v[1].x*a.y - v[1].y*a.x; }
        if (2 < MCH) { float2 a = col[lc][2];
          wr += v[2].x*a.x + v[2].y*a.y; wi += v[2].x*a.y - v[2].y*a.x; }
        if (3 < MCH) { float2 a = col[lc][3];
          wr += v[3].x*a.x + v[3].y*a.y; wi += v[3].x*a.y - v[3].y*a.x; }
        #pragma unroll
        for (int s = 32; s; s >>= 1) { wr += __shfl_xor(wr, s);
                                       wi += __shfl_xor(wi, s); }
        float fr = taur*wr + taui*wi;                  // f = conj(tau)*w
        float fi = taur*wi - taui*wr;
        { col[lc][0].x -= fr*v[0].x - fi*v[0].y;
          col[lc][0].y -= fr*v[0].y + fi*v[0].x; }
        if (1 < MCH) { col[lc][1].x -= fr*v[1].x - fi*v[1].y;
                       col[lc][1].y -= fr*v[1].y + fi*v[1].x; }
        if (2 < MCH) { col[lc][2].x -= fr*v[2].x - fi*v[2].y;
                       col[lc][2].y -= fr*v[2].y + fi*v[2].x; }
        if (3 < MCH) { col[lc][3].x -= fr*v[3].x - fi*v[3].y;
                       col[lc][3].y -= fr*v[3].y + fi*v[3].x; }
        if (cl == jl + 1) {
          #pragma unroll
          for (int m = 0; m < 4; ++m) snext[nxt][m*64 + lane] = col[lc][m];
        }
      }
    }
    __syncthreads();
  }
}

// ---------------------------------------------------------------------------
// Apply panel j0's 32 reflectors to a 32-column trailing tile (registers).
// V-panel staged ONCE into LDS (64 KB): per-reflector work is pure LDS/VALU,
// removing the serial per-reflector L2 v-load chain.
// ---------------------------------------------------------------------------
__global__ __launch_bounds__(256, 1) void qr_apply_kernel(
    float2* __restrict__ A, const float2* __restrict__ tau, int j0)
{
  const int tid = threadIdx.x, lane = tid & 63, w = tid >> 6;
  const int R = 256 - j0;
  const int MCH = (R + 63) >> 6;
  const int c0 = j0 + 32 + blockIdx.x * 32;
  __shared__ float2 sv32[32][256];
  __shared__ float2 stau32[32];

  #pragma unroll 1
  for (int c = 0; c < 32; ++c)
    sv32[c][tid] = (tid < R) ? A[(size_t)(j0+c)*D_ + j0 + tid]
                             : make_float2(0.f, 0.f);
  if (tid < 32) stau32[tid] = tau[j0 + tid];

  float2 col[8][4];
  #pragma unroll
  for (int lc = 0; lc < 8; ++lc) {
    int cg = c0 + lc*4 + w;
    #pragma unroll
    for (int m = 0; m < 4; ++m) {
      int rr = m*64 + lane;
      col[lc][m] = make_float2(0.f, 0.f);
      if (m < MCH && rr < R) col[lc][m] = A[(size_t)cg*D_ + j0 + rr];
    }
  }
  __syncthreads();

  #pragma unroll 1
  for (int jl = 0; jl < 32; ++jl) {
    float2 tt = stau32[jl];
    float2 v[4];
    {
      float2 raw = sv32[jl][lane];
      v[0] = (lane > jl) ? raw : ((lane == jl) ? make_float2(1.f, 0.f)
                                               : make_float2(0.f, 0.f));
    }
    #pragma unroll
    for (int m = 1; m < 4; ++m) v[m] = sv32[jl][m*64 + lane];  // rows>63>jl

    float wr[8], wi[8];
    #pragma unroll
    for (int lc = 0; lc < 8; ++lc) {
      wr[lc] = 0.f; wi[lc] = 0.f;
      #pragma unroll
      for (int m = 0; m < 4; ++m) {
        if (m < MCH) {
          float2 a = col[lc][m];
          wr[lc] += v[m].x*a.x + v[m].y*a.y;
          wi[lc] += v[m].x*a.y - v[m].y*a.x;
        }
      }
    }
    #pragma unroll
    for (int lc = 0; lc < 8; ++lc) {
      #pragma unroll
      for (int s = 32; s; s >>= 1) { wr[lc] += __shfl_xor(wr[lc], s);
                                     wi[lc] += __shfl_xor(wi[lc], s); }
    }
    #pragma unroll
    for (int lc = 0; lc < 8; ++lc) {
      float fr = tt.x*wr[lc] + tt.y*wi[lc];            // f = conj(tau)*w
      float fi = tt.x*wi[lc] - tt.y*wr[lc];
      #pragma unroll
      for (int m = 0; m < 4; ++m) {
        if (m < MCH) {
          col[lc][m].x -= fr*v[m].x - fi*v[m].y;
          col[lc][m].y -= fr*v[m].y + fi*v[m].x;
        }
      }
    }
  }
  #pragma unroll
  for (int lc = 0; lc < 8; ++lc) {
    int cg = c0 + lc*4 + w;
    #pragma unroll
    for (int m = 0; m < 4; ++m) {
      int rr = m*64 + lane;
      if (m < MCH && rr < R) A[(size_t)cg*D_ + j0 + rr] = col[lc][m];
    }
  }
}

// ---------------------------------------------------------------------------
// zung2r: column c of Q = H_0(...H_c(e_c)); one wave per column; depth-2
// register prefetch (a0/a1/a2 rotation) keeps 2 reflector columns in flight.
// Epilogue writes bf16 B^T matrices for both GEMMs:
//   Benc [512][256]: rows 0..255 = Re(Q)^T, rows 256.. = Im(Q)^T
//   Bdec [512][512]: [n][k]: n<256,k<256: ur[k][n]; n<256,k>=256: -ui
//                    n>=256,k<256: ui;             n>=256,k>=256: ur
// ---------------------------------------------------------------------------
__global__ __launch_bounds__(256, 1) void qr_bwd_kernel(
    const float2* __restrict__ A, const float2* __restrict__ tau,
    u16* __restrict__ Benc, u16* __restrict__ Bdec)
{
  const int lane = threadIdx.x & 63;
  const int w = threadIdx.x >> 6;
  const int c = blockIdx.x * 4 + w;          // column 0..255
  __shared__ float2 stau[256];
  if (threadIdx.x < 256) stau[threadIdx.x] = tau[threadIdx.x];
  __syncthreads();

  float2 q[4];
  #pragma unroll
  for (int m = 0; m < 4; ++m) {
    q[m] = make_float2(0.f, 0.f);
    if (m*64 + lane == c) q[m].x = 1.f;      // q = e_c
  }
  float2 a0[4], a1[4];
  #pragma unroll
  for (int m = 0; m < 4; ++m) a0[m] = A[(size_t)c*D_ + m*64 + lane];
  {
    int i1 = (c >= 1) ? c - 1 : 0;
    #pragma unroll
    for (int m = 0; m < 4; ++m) a1[m] = A[(size_t)i1*D_ + m*64 + lane];
  }

  #pragma unroll 1
  for (int i = c; i >= 0; --i) {
    int ip = (i >= 2) ? i - 2 : 0;
    float2 a2[4];
    #pragma unroll
    for (int m = 0; m < 4; ++m) a2[m] = A[(size_t)ip*D_ + m*64 + lane];

    float2 tt = stau[i];
    float2 v[4];
    #pragma unroll
    for (int m = 0; m < 4; ++m) {
      int r = m*64 + lane;
      v[m] = (r > i) ? a0[m] : ((r == i) ? make_float2(1.f, 0.f)
                                         : make_float2(0.f, 0.f));
    }
    float wr = 0.f, wi = 0.f;
    #pragma unroll
    for (int m = 0; m < 4; ++m) {
      wr += v[m].x*q[m].x + v[m].y*q[m].y;   // w += conj(v)*q
      wi += v[m].x*q[m].y - v[m].y*q[m].x;
    }
    #pragma unroll
    for (int s = 32; s; s >>= 1) { wr += __shfl_xor(wr, s); wi += __shfl_xor(wi, s); }
    float fr = tt.x*wr - tt.y*wi;            // f = tau*w (0 when tau==0)
    float fi = tt.x*wi + tt.y*wr;
    #pragma unroll
    for (int m = 0; m < 4; ++m) {
      q[m].x -= fr*v[m].x - fi*v[m].y;
      q[m].y -= fr*v[m].y + fi*v[m].x;
      a0[m] = a1[m]; a1[m] = a2[m];
    }
  }

  #pragma unroll
  for (int m = 0; m < 4; ++m) {
    int r = m*64 + lane;
    u16 qre = f2bf(q[m].x), qim = f2bf(q[m].y), qimn = f2bf(-q[m].y);
    Benc[(size_t)c*D_ + r]              = qre;
    Benc[(size_t)(c+256)*D_ + r]        = qim;
    Bdec[(size_t)c*512 + r]             = qre;
    Bdec[(size_t)c*512 + 256 + r]       = qimn;
    Bdec[(size_t)(c+256)*512 + r]       = qim;
    Bdec[(size_t)(c+256)*512 + 256 + r] = qre;
  }
}

// ---------------------------------------------------------------------------
// Per-(b,t,d) coefficients (tables; avoids 270M transcendentals in scan).
// ---------------------------------------------------------------------------
__global__ __launch_bounds__(256) void coef_kernel(
  const float* __restrict__ dt, const float* __restrict__ lam_re, const float* __restrict__ lam_im,
  const float* __restrict__ noise_raw,
  float* __restrict__ c_dre, float* __restrict__ c_dim, float* __restrict__ c_fre,
  float* __restrict__ c_fim, float* __restrict__ c_ns)
{
  int bt = blockIdx.x; int d = threadIdx.x;
  float dtv = dt[bt];
  float lr = lam_re[d], li = lam_im[d];
  float lam_r = fmaxf(-log1pf(expf(-lr)), -0.3f);
  float ar = dtv*lam_r, ai = dtv*li;
  float er = expf(ar);
  float dre = er*cosf(ai), dim_ = er*sinf(ai);
  float t = lam_r + 1e-12f;
  float sgn = (t > 0.f) ? 1.f : ((t < 0.f) ? -1.f : 0.f);
  float den_re = lam_r + 1e-8f*sgn, den_im = li;
  float nr = dre - 1.f, ni = dim_;
  float d2 = den_re*den_re + den_im*den_im;
  float fre = (nr*den_re + ni*den_im)/d2;
  float fim = (ni*den_re - nr*den_im)/d2;
  float ns = sqrtf(fmaxf(dtv,0.f)) * log1pf(expf(noise_raw[d])) * 0.01f;
  int idx = bt*D_+d;
  c_dre[idx]=dre; c_dim[idx]=dim_; c_fre[idx]=fre; c_fim[idx]=fim; c_ns[idx]=ns;
}

// ---------------------------------------------------------------------------
// bf16 MFMA GEMM, 128x128 tile, 4 waves, BK=64, 16x16x32 MFMA.
// encode_gemm reads fp32 x directly and converts during staging (xconv fused).
// LDS row stride 72 elements (144 B): 16B-aligned, 2-way banks (free).
// ---------------------------------------------------------------------------
#define LDT 72

__global__ __launch_bounds__(256) void encode_gemm(
    const float* __restrict__ x, const u16* __restrict__ Bt,
    u16* __restrict__ xer16, u16* __restrict__ xei16)
{
  __shared__ u16 sA[128*LDT];
  __shared__ u16 sB[128*LDT];
  const int tid = threadIdx.x;
  const int lane = tid & 63, w = tid >> 6;
  const int wr = w >> 1, wc = w & 1;
  const int l15 = lane & 15, l4 = lane >> 4;
  const int m0 = blockIdx.x * 128;
  const int n0 = blockIdx.y * 128;
  f32x4 acc[4][4] = {};
  for (int kb = 0; kb < 4; ++kb) {
    #pragma unroll
    for (int i = 0; i < 4; ++i) {
      int chunk = i*256 + tid;
      int row = chunk >> 3, k0 = (chunk & 7) * 8;
      const float* xs = x + (size_t)(m0+row)*D_ + kb*64 + k0;
      float4 f0 = *(const float4*)xs;
      float4 f1 = *(const float4*)(xs + 4);
      int4 va;
      va.x = (int)((unsigned)f2bf(f0.x) | ((unsigned)f2bf(f0.y) << 16));
      va.y = (int)((unsigned)f2bf(f0.z) | ((unsigned)f2bf(f0.w) << 16));
      va.z = (int)((unsigned)f2bf(f1.x) | ((unsigned)f2bf(f1.y) << 16));
      va.w = (int)((unsigned)f2bf(f1.z) | ((unsigned)f2bf(f1.w) << 16));
      int4 vb = *(const int4*)(Bt + (size_t)(n0+row)*D_ + kb*64 + k0);
      *(int4*)&sA[row*LDT + k0] = va;
      *(int4*)&sB[row*LDT + k0] = vb;
    }
    __syncthreads();
    #pragma unroll
    for (int ks = 0; ks < 2; ++ks) {
      bf16x8 af[4], bb[4];
      #pragma unroll
      for (int mf = 0; mf < 4; ++mf)
        af[mf] = *(const bf16x8*)&sA[(wr*64 + mf*16 + l15)*LDT + ks*32 + l4*8];
      #pragma unroll
      for (int nf = 0; nf < 4; ++nf)
        bb[nf] = *(const bf16x8*)&sB[(wc*64 + nf*16 + l15)*LDT + ks*32 + l4*8];
      #pragma unroll
      for (int mf = 0; mf < 4; ++mf)
        #pragma unroll
        for (int nf = 0; nf < 4; ++nf)
          acc[mf][nf] = __builtin_amdgcn_mfma_f32_16x16x32_bf16(
              af[mf], bb[nf], acc[mf][nf], 0, 0, 0);
    }
    __syncthreads();
  }
  #pragma unroll
  for (int mf = 0; mf < 4; ++mf)
    #pragma unroll
    for (int nf = 0; nf < 4; ++nf)
      #pragma unroll
      for (int r = 0; r < 4; ++r) {
        int row = m0 + wr*64 + mf*16 + l4*4 + r;
        int col = n0 + wc*64 + nf*16 + l15;
        float v = acc[mf][nf][r];
        if (col < 256) xer16[(size_t)row*D_ + col] = f2bf(v);
        else           xei16[(size_t)row*D_ + col - 256] = f2bf(-v);
      }
}

__global__ __launch_bounds__(256) void decode_gemm(
    const u16* __restrict__ hre16, const u16* __restrict__ him16,
    const u16* __restrict__ Bt, float* __restrict__ out)
{
  __shared__ u16 sA[128*LDT];
  __shared__ u16 sB[128*LDT];
  const int tid = threadIdx.x;
  const int lane = tid & 63, w = tid >> 6;
  const int wr = w >> 1, wc = w & 1;
  const int l15 = lane & 15, l4 = lane >> 4;
  const int m0 = blockIdx.x * 128;
  const int n0 = blockIdx.y * 128;
  f32x4 acc[4][4] = {};
  for (int kb = 0; kb < 8; ++kb) {
    const u16* aplane = (kb < 4) ? hre16 : him16;
    const int kk = (kb & 3) * 64;
    #pragma unroll
    for (int i = 0; i < 4; ++i) {
      int chunk = i*256 + tid;
      int row = chunk >> 3, k0 = (chunk & 7) * 8;
      int4 va = *(const int4*)(aplane + (size_t)(m0+row)*D_ + kk + k0);
      int4 vb = *(const int4*)(Bt + (size_t)(n0+row)*512 + kb*64 + k0);
      *(int4*)&sA[row*LDT + k0] = va;
      *(int4*)&sB[row*LDT + k0] = vb;
    }
    __syncthreads();
    #pragma unroll
    for (int ks = 0; ks < 2; ++ks) {
      bf16x8 af[4], bb[4];
      #pragma unroll
      for (int mf = 0; mf < 4; ++mf)
        af[mf] = *(const bf16x8*)&sA[(wr*64 + mf*16 + l15)*LDT + ks*32 + l4*8];
      #pragma unroll
      for (int nf = 0; nf < 4; ++nf)
        bb[nf] = *(const bf16x8*)&sB[(wc*64 + nf*16 + l15)*LDT + ks*32 + l4*8];
      #pragma unroll
      for (int mf = 0; mf < 4; ++mf)
        #pragma unroll
        for (int nf = 0; nf < 4; ++nf)
          acc[mf][nf] = __builtin_amdgcn_mfma_f32_16x16x32_bf16(
              af[mf], bb[nf], acc[mf][nf], 0, 0, 0);
    }
    __syncthreads();
  }
  #pragma unroll
  for (int mf = 0; mf < 4; ++mf)
    #pragma unroll
    for (int nf = 0; nf < 4; ++nf)
      #pragma unroll
      for (int r = 0; r < 4; ++r) {
        int row = m0 + wr*64 + mf*16 + l4*4 + r;
        int col = n0 + wc*64 + nf*16 + l15;
        float v = acc[mf][nf][r];
        if (col < 256) out[(size_t)row*D_ + col] = v;
        else           out[PLANE + (size_t)row*D_ + col - 256] = v;
      }
}

// ---------------------------------------------------------------------------
// Scan: reads bf16 x_enc planes + fp32 eps + coef tables (L2-resident);
// writes bf16 h planes. One block per (b,n); thread = d.
// ---------------------------------------------------------------------------
__global__ __launch_bounds__(256) void scan_kernel(
  const float* __restrict__ eps,
  const float* __restrict__ c_dre, const float* __restrict__ c_dim,
  const float* __restrict__ c_fre, const float* __restrict__ c_fim, const float* __restrict__ c_ns,
  const u16* __restrict__ xer16, const u16* __restrict__ xei16,
  u16* __restrict__ hre16, u16* __restrict__ him16)
{
  int bx = blockIdx.x;
  int b = bx >> 9, n = bx & 511;
  int d = threadIdx.x;
  float hr = 0.f, hi = 0.f;
  for (int t = 0; t < T_; ++t) {
    int bt = b*T_ + t;
    int cidx = bt*D_ + d;
    float dre = c_dre[cidx], dim_ = c_dim[cidx];
    float fre = c_fre[cidx], fim = c_fim[cidx];
    float ns  = c_ns[cidx];
    size_t idx = ((size_t)bt*N_ + n)*D_ + d;
    float xr = bf2f(xer16[idx]), xi = bf2f(xei16[idx]), ep = eps[idx];
    float br = fre*xr - fim*xi + ep*ns;
    float bi = fre*xi + fim*xr;
    float nr2 = dre*hr - dim_*hi + br;
    float ni2 = dre*hi + dim_*hr + bi;
    hr = nr2; hi = ni2;
    hre16[idx] = f2bf(hr); him16[idx] = f2bf(hi);
  }
}

// ---------------------------------------------------------------------------
extern "C" void kernel_launch(void* const* d_in, const int* in_sizes, int n_in,
                              void* d_out, int out_size, void* d_ws, size_t ws_size,
                              hipStream_t stream)
{
  const float* x         = (const float*)d_in[0];
  const float* dt        = (const float*)d_in[1];
  const float* eps       = (const float*)d_in[2];
  const float* ure_raw   = (const float*)d_in[3];
  const float* uim_raw   = (const float*)d_in[4];
  const float* lam_re    = (const float*)d_in[5];
  const float* lam_im    = (const float*)d_in[6];
  const float* noise_raw = (const float*)d_in[7];
  float* out = (float*)d_out;

  // ws layout (132 MB total):
  //   0       A float2[65536]            512 KB
  //   512K    tau float2[256]
  //   1M      Benc bf16 [512][256]       256 KB
  //   1.5M    Bdec bf16 [512][512]       512 KB
  //   2M      coef tables 5 x 64 KB      320 KB
  //   4M      hre16 bf16 [M][256] 32 MB
  //   36M     xer16 32 MB
  //   68M     xei16 32 MB
  //   100M    him16 32 MB
  char* ws = (char*)d_ws;
  float2* A    = (float2*)(ws);
  float2* tau  = (float2*)(ws + 524288);
  u16* Benc    = (u16*)(ws + (1<<20));
  u16* Bdec    = (u16*)(ws + 1572864);
  float* c_dre = (float*)(ws + (2<<20));
  float* c_dim = c_dre + B_*T_*D_;
  float* c_fre = c_dim + B_*T_*D_;
  float* c_fim = c_fre + B_*T_*D_;
  float* c_ns  = c_fim + B_*T_*D_;
  u16* hre16   = (u16*)(ws + ((size_t)4<<20));
  u16* xer16   = (u16*)(ws + ((size_t)36<<20));
  u16* xei16   = (u16*)(ws + ((size_t)68<<20));
  u16* him16   = (u16*)(ws + ((size_t)100<<20));

  qr_init_kernel<<<64, 1024, 0, stream>>>(ure_raw, uim_raw, A);
  for (int p = 0; p < 8; ++p) {
    qr_panel_kernel<<<1, 256, 0, stream>>>(A, tau, 32*p);
    int nb = 7 - p;
    if (nb > 0) qr_apply_kernel<<<nb, 256, 0, stream>>>(A, tau, 32*p);
  }
  qr_bwd_kernel<<<64, 256, 0, stream>>>(A, tau, Benc, Bdec);
  coef_kernel<<<B_*T_, 256, 0, stream>>>(dt, lam_re, lam_im, noise_raw,
                                         c_dre, c_dim, c_fre, c_fim, c_ns);
  encode_gemm<<<dim3(M_/128, 4), 256, 0, stream>>>(x, Benc, xer16, xei16);
  scan_kernel<<<B_*N_, 256, 0, stream>>>(eps, c_dre, c_dim, c_fre, c_fim, c_ns,
                                         xer16, xei16, hre16, him16);
  decode_gemm<<<dim3(M_/128, 4), 256, 0, stream>>>(hre16, him16, Bdec, out);
}

// Round 8
// 1446.978 us; speedup vs baseline: 1.7782x; 1.0323x over previous
//
#include <hip/hip_runtime.h>
#include <math.h>

// Problem constants (B,T,N,D) = (2,64,512,256)
#define B_ 2
#define T_ 64
#define N_ 512
#define D_ 256
#define M_ (B_*T_*N_)            // 65536 rows for the GEMMs
#define PLANE ((size_t)M_*D_)    // 16777216 elements per output plane

typedef unsigned short u16;
typedef __attribute__((ext_vector_type(8))) short bf16x8;
typedef __attribute__((ext_vector_type(4))) float f32x4;

__device__ __forceinline__ u16 f2bf(float f) {
  union { float f; unsigned u; } cv; cv.f = f;
  unsigned u = cv.u;
  return (u16)((u + 0x7FFFu + ((u >> 16) & 1u)) >> 16);   // RNE
}
__device__ __forceinline__ float bf2f(u16 h) {
  union { unsigned u; float f; } cv; cv.u = ((unsigned)h) << 16;
  return cv.f;
}

// ---------------------------------------------------------------------------
// Megastep p: ONE launch = [apply V_{p-1} to all trailing panels, in parallel
// across blocks] + [factorize panel p in block 0]. Cuts 16 QR-fwd launches to
// 8 and runs panel/apply concurrently (they're block-independent):
//   role 0:   (p>0: apply V_{p-1} to panel p's 32 cols), factorize panel p.
//   role r>0: p==0: transpose-init panel r cols from raw.
//             p>0 : apply V_{p-1} to panel (p+r) cols.
// Register window for role 0 starts at j0_prev with pivot offset piv=32, so
// the pivot row (32+jl < 64) stays in register chunk 0 -> all register
// indices compile-time (rule #20). Pivot column flows through LDS snext.
// ---------------------------------------------------------------------------
__global__ __launch_bounds__(256, 1) void qr_megastep(
    const float* __restrict__ ure_raw, const float* __restrict__ uim_raw,
    float2* __restrict__ A, float2* __restrict__ tau, int p)
{
  const int tid = threadIdx.x, lane = tid & 63, w = tid >> 6;
  const int role = blockIdx.x;
  __shared__ float2 sv32[32][256];
  __shared__ float2 stau32[32];
  __shared__ float2 snext[2][256];

  if (p == 0 && role > 0) {
    // transpose-init panel `role`: A[c][r] = raw[r][c]; coalesced raw reads
    const int c0 = 32*role;
    const int c = tid & 31, r0 = tid >> 5;
    for (int r8 = 0; r8 < 32; ++r8) {
      int r = r0 + r8*8;
      A[(size_t)(c0+c)*D_ + r] = make_float2(ure_raw[(size_t)r*D_ + c0 + c],
                                             uim_raw[(size_t)r*D_ + c0 + c]);
    }
    return;
  }

  const int j0p  = 32*(p - 1);          // prev-panel start (valid p>=1)
  const int Rp   = 256 - j0p;
  const int MCHp = (Rp + 63) >> 6;

  if (role > 0) {
    // ===== apply V_{p-1} to panel (p+role) =====
    for (int c = 0; c < 32; ++c) {
      float2 val = make_float2(0.f, 0.f);
      if (tid < Rp) val = A[(size_t)(j0p+c)*D_ + j0p + tid];
      sv32[c][tid] = val;
    }
    if (tid < 32) stau32[tid] = tau[j0p + tid];
    const int c0 = 32*(p + role);
    float2 col[8][4];
    #pragma unroll
    for (int lc = 0; lc < 8; ++lc) {
      int cg = c0 + lc*4 + w;
      #pragma unroll
      for (int m = 0; m < 4; ++m) {
        int rr = m*64 + lane;
        col[lc][m] = make_float2(0.f, 0.f);
        if (m < MCHp && rr < Rp) col[lc][m] = A[(size_t)cg*D_ + j0p + rr];
      }
    }
    __syncthreads();
    #pragma unroll 1
    for (int jl = 0; jl < 32; ++jl) {
      float2 tt = stau32[jl];
      float2 v[4];
      { float2 rv = sv32[jl][lane];
        v[0] = (lane > jl) ? rv : ((lane == jl) ? make_float2(1.f, 0.f)
                                                : make_float2(0.f, 0.f)); }
      #pragma unroll
      for (int m = 1; m < 4; ++m) v[m] = sv32[jl][m*64 + lane];
      float wr[8], wi[8];
      #pragma unroll
      for (int lc = 0; lc < 8; ++lc) {
        wr[lc] = 0.f; wi[lc] = 0.f;
        #pragma unroll
        for (int m = 0; m < 4; ++m) {
          if (m < MCHp) {
            float2 a = col[lc][m];
            wr[lc] += v[m].x*a.x + v[m].y*a.y;
            wi[lc] += v[m].x*a.y - v[m].y*a.x;
          }
        }
      }
      #pragma unroll
      for (int lc = 0; lc < 8; ++lc) {
        #pragma unroll
        for (int s = 32; s; s >>= 1) { wr[lc] += __shfl_xor(wr[lc], s);
                                       wi[lc] += __shfl_xor(wi[lc], s); }
      }
      #pragma unroll
      for (int lc = 0; lc < 8; ++lc) {
        float fr = tt.x*wr[lc] + tt.y*wi[lc];          // f = conj(tau)*w
        float fi = tt.x*wi[lc] - tt.y*wr[lc];
        #pragma unroll
        for (int m = 0; m < 4; ++m) {
          if (m < MCHp) {
            col[lc][m].x -= fr*v[m].x - fi*v[m].y;
            col[lc][m].y -= fr*v[m].y + fi*v[m].x;
          }
        }
      }
    }
    #pragma unroll
    for (int lc = 0; lc < 8; ++lc) {
      int cg = c0 + lc*4 + w;
      #pragma unroll
      for (int m = 0; m < 4; ++m) {
        int rr = m*64 + lane;
        if (m < MCHp && rr < Rp) A[(size_t)cg*D_ + j0p + rr] = col[lc][m];
      }
    }
    return;
  }

  // ===== role 0: panel p =====
  const int piv  = (p == 0) ? 0 : 32;       // pivot offset inside window
  const int j0w  = (p == 0) ? 0 : j0p;      // register window start row
  const int Rw   = 256 - j0w;
  const int MCHw = (Rw + 63) >> 6;

  float2 col[8][4];
  if (p == 0) {
    #pragma unroll
    for (int lc = 0; lc < 8; ++lc) {
      int cg = lc*4 + w;
      #pragma unroll
      for (int m = 0; m < 4; ++m) {
        int rr = m*64 + lane;
        col[lc][m] = make_float2(ure_raw[(size_t)rr*D_ + cg],
                                 uim_raw[(size_t)rr*D_ + cg]);
      }
    }
  } else {
    for (int c = 0; c < 32; ++c) {
      float2 val = make_float2(0.f, 0.f);
      if (tid < Rp) val = A[(size_t)(j0p+c)*D_ + j0p + tid];
      sv32[c][tid] = val;
    }
    if (tid < 32) stau32[tid] = tau[j0p + tid];
    #pragma unroll
    for (int lc = 0; lc < 8; ++lc) {
      int cg = 32*p + lc*4 + w;
      #pragma unroll
      for (int m = 0; m < 4; ++m) {
        int rr = m*64 + lane;
        col[lc][m] = make_float2(0.f, 0.f);
        if (m < MCHp && rr < Rp) col[lc][m] = A[(size_t)cg*D_ + j0p + rr];
      }
    }
    __syncthreads();
    // apply V_{p-1} to own 32 columns
    #pragma unroll 1
    for (int jl = 0; jl < 32; ++jl) {
      float2 tt = stau32[jl];
      float2 v[4];
      { float2 rv = sv32[jl][lane];
        v[0] = (lane > jl) ? rv : ((lane == jl) ? make_float2(1.f, 0.f)
                                                : make_float2(0.f, 0.f)); }
      #pragma unroll
      for (int m = 1; m < 4; ++m) v[m] = sv32[jl][m*64 + lane];
      float wr[8], wi[8];
      #pragma unroll
      for (int lc = 0; lc < 8; ++lc) {
        wr[lc] = 0.f; wi[lc] = 0.f;
        #pragma unroll
        for (int m = 0; m < 4; ++m) {
          if (m < MCHp) {
            float2 a = col[lc][m];
            wr[lc] += v[m].x*a.x + v[m].y*a.y;
            wi[lc] += v[m].x*a.y - v[m].y*a.x;
          }
        }
      }
      #pragma unroll
      for (int lc = 0; lc < 8; ++lc) {
        #pragma unroll
        for (int s = 32; s; s >>= 1) { wr[lc] += __shfl_xor(wr[lc], s);
                                       wi[lc] += __shfl_xor(wi[lc], s); }
      }
      #pragma unroll
      for (int lc = 0; lc < 8; ++lc) {
        float fr = tt.x*wr[lc] + tt.y*wi[lc];
        float fi = tt.x*wi[lc] - tt.y*wr[lc];
        #pragma unroll
        for (int m = 0; m < 4; ++m) {
          if (m < MCHp) {
            col[lc][m].x -= fr*v[m].x - fi*v[m].y;
            col[lc][m].y -= fr*v[m].y + fi*v[m].x;
          }
        }
      }
    }
  }

  if (w == 0) {
    #pragma unroll
    for (int m = 0; m < 4; ++m) snext[0][m*64 + lane] = col[0][m];
  }
  __syncthreads();

  // factorize 32 reflectors; pivot row = piv + jl (always in chunk 0)
  #pragma unroll 1
  for (int jl = 0; jl < 32; ++jl) {
    const int cur = jl & 1, nxt = cur ^ 1;
    float2 pc[4];
    #pragma unroll
    for (int m = 0; m < 4; ++m) pc[m] = snext[cur][m*64 + lane];
    float part = (lane > piv + jl) ? (pc[0].x*pc[0].x + pc[0].y*pc[0].y) : 0.f;
    if (1 < MCHw) part += pc[1].x*pc[1].x + pc[1].y*pc[1].y;
    if (2 < MCHw) part += pc[2].x*pc[2].x + pc[2].y*pc[2].y;
    if (3 < MCHw) part += pc[3].x*pc[3].x + pc[3].y*pc[3].y;
    #pragma unroll
    for (int s = 32; s; s >>= 1) part += __shfl_xor(part, s);
    float ar = __shfl(pc[0].x, piv + jl), ai = __shfl(pc[0].y, piv + jl);
    float taur, taui, sclr, scli, beta;
    if (part == 0.f && ai == 0.f) {
      taur = taui = sclr = scli = 0.f; beta = ar;      // H = I
    } else {
      float nrm = sqrtf(ar*ar + ai*ai + part);
      beta = (ar >= 0.f) ? -nrm : nrm;                 // -SIGN(nrm, Re(alpha))
      taur = (beta - ar)/beta; taui = -ai/beta;
      float dr = ar - beta, di = ai, dn = dr*dr + di*di;
      sclr = dr/dn; scli = -di/dn;                     // 1/(alpha-beta)
    }
    if (w == 3 && lane == 0) tau[32*p + jl] = make_float2(taur, taui);
    float2 v[4];
    {
      float2 t0 = make_float2(pc[0].x*sclr - pc[0].y*scli,
                              pc[0].x*scli + pc[0].y*sclr);
      v[0] = (lane > piv + jl) ? t0 : ((lane == piv + jl)
                 ? make_float2(1.f, 0.f) : make_float2(0.f, 0.f));
    }
    #pragma unroll
    for (int m = 1; m < 4; ++m)
      v[m] = make_float2(pc[m].x*sclr - pc[m].y*scli,
                         pc[m].x*scli + pc[m].y*sclr);
    if (w == 3) {
      #pragma unroll
      for (int m = 0; m < 4; ++m) {
        int rr = m*64 + lane;
        float2 o = v[m];
        if (m == 0) {
          if (lane < piv + jl)       o = pc[0];
          else if (lane == piv + jl) o = make_float2(beta, 0.f);
        }
        if (m < MCHw && rr < Rw) A[(size_t)(32*p + jl)*D_ + j0w + rr] = o;
      }
    }
    #pragma unroll
    for (int lc = 0; lc < 8; ++lc) {
      int cl = lc*4 + w;
      if (cl > jl) {
        float wr, wi;
        { float2 a = col[lc][0];
          wr = v[0].x*a.x + v[0].y*a.y; wi = v[0].x*a.y - v[0].y*a.x; }
        if (1 < MCHw) { float2 a = col[lc][1];
          wr += v[1].x*a.x + v[1].y*a.y; wi += v[1].x*a.y - v[1].y*a.x; }
        if (2 < MCHw) { float2 a = col[lc][2];
          wr += v[2].x*a.x + v[2].y*a.y; wi += v[2].x*a.y - v[2].y*a.x; }
        if (3 < MCHw) { float2 a = col[lc][3];
          wr += v[3].x*a.x + v[3].y*a.y; wi += v[3].x*a.y - v[3].y*a.x; }
        #pragma unroll
        for (int s = 32; s; s >>= 1) { wr += __shfl_xor(wr, s);
                                       wi += __shfl_xor(wi, s); }
        float fr = taur*wr + taui*wi;                  // f = conj(tau)*w
        float fi = taur*wi - taui*wr;
        { col[lc][0].x -= fr*v[0].x - fi*v[0].y;
          col[lc][0].y -= fr*v[0].y + fi*v[0].x; }
        if (1 < MCHw) { col[lc][1].x -= fr*v[1].x - fi*v[1].y;
                        col[lc][1].y -= fr*v[1].y + fi*v[1].x; }
        if (2 < MCHw) { col[lc][2].x -= fr*v[2].x - fi*v[2].y;
                        col[lc][2].y -= fr*v[2].y + fi*v[2].x; }
        if (3 < MCHw) { col[lc][3].x -= fr*v[3].x - fi*v[3].y;
                        col[lc][3].y -= fr*v[3].y + fi*v[3].x; }
        if (cl == jl + 1) {
          #pragma unroll
          for (int m = 0; m < 4; ++m) snext[nxt][m*64 + lane] = col[lc][m];
        }
      }
    }
    __syncthreads();
  }
}

// ---------------------------------------------------------------------------
// zung2r: column c of Q = H_0(...H_c(e_c)); one wave per column; depth-2
// register prefetch. Epilogue writes bf16 B^T matrices for both GEMMs.
// ---------------------------------------------------------------------------
__global__ __launch_bounds__(256, 1) void qr_bwd_kernel(
    const float2* __restrict__ A, const float2* __restrict__ tau,
    u16* __restrict__ Benc, u16* __restrict__ Bdec)
{
  const int lane = threadIdx.x & 63;
  const int w = threadIdx.x >> 6;
  const int c = blockIdx.x * 4 + w;          // column 0..255
  __shared__ float2 stau[256];
  if (threadIdx.x < 256) stau[threadIdx.x] = tau[threadIdx.x];
  __syncthreads();

  float2 q[4];
  #pragma unroll
  for (int m = 0; m < 4; ++m) {
    q[m] = make_float2(0.f, 0.f);
    if (m*64 + lane == c) q[m].x = 1.f;      // q = e_c
  }
  float2 a0[4], a1[4];
  #pragma unroll
  for (int m = 0; m < 4; ++m) a0[m] = A[(size_t)c*D_ + m*64 + lane];
  {
    int i1 = (c >= 1) ? c - 1 : 0;
    #pragma unroll
    for (int m = 0; m < 4; ++m) a1[m] = A[(size_t)i1*D_ + m*64 + lane];
  }

  #pragma unroll 1
  for (int i = c; i >= 0; --i) {
    int ip = (i >= 2) ? i - 2 : 0;
    float2 a2[4];
    #pragma unroll
    for (int m = 0; m < 4; ++m) a2[m] = A[(size_t)ip*D_ + m*64 + lane];

    float2 tt = stau[i];
    float2 v[4];
    #pragma unroll
    for (int m = 0; m < 4; ++m) {
      int r = m*64 + lane;
      v[m] = (r > i) ? a0[m] : ((r == i) ? make_float2(1.f, 0.f)
                                         : make_float2(0.f, 0.f));
    }
    float wr = 0.f, wi = 0.f;
    #pragma unroll
    for (int m = 0; m < 4; ++m) {
      wr += v[m].x*q[m].x + v[m].y*q[m].y;   // w += conj(v)*q
      wi += v[m].x*q[m].y - v[m].y*q[m].x;
    }
    #pragma unroll
    for (int s = 32; s; s >>= 1) { wr += __shfl_xor(wr, s); wi += __shfl_xor(wi, s); }
    float fr = tt.x*wr - tt.y*wi;            // f = tau*w (0 when tau==0)
    float fi = tt.x*wi + tt.y*wr;
    #pragma unroll
    for (int m = 0; m < 4; ++m) {
      q[m].x -= fr*v[m].x - fi*v[m].y;
      q[m].y -= fr*v[m].y + fi*v[m].x;
      a0[m] = a1[m]; a1[m] = a2[m];
    }
  }

  #pragma unroll
  for (int m = 0; m < 4; ++m) {
    int r = m*64 + lane;
    u16 qre = f2bf(q[m].x), qim = f2bf(q[m].y), qimn = f2bf(-q[m].y);
    Benc[(size_t)c*D_ + r]              = qre;
    Benc[(size_t)(c+256)*D_ + r]        = qim;
    Bdec[(size_t)c*512 + r]             = qre;
    Bdec[(size_t)c*512 + 256 + r]       = qimn;
    Bdec[(size_t)(c+256)*512 + r]       = qim;
    Bdec[(size_t)(c+256)*512 + 256 + r] = qre;
  }
}

// ---------------------------------------------------------------------------
// bf16 MFMA GEMM, 128x128 tile, 4 waves, BK=64, 16x16x32 MFMA.
// encode_gemm reads fp32 x directly and converts during staging.
// LDS row stride 72 elements (144 B): 16B-aligned, 2-way banks (free).
// ---------------------------------------------------------------------------
#define LDT 72

__global__ __launch_bounds__(256) void encode_gemm(
    const float* __restrict__ x, const u16* __restrict__ Bt,
    u16* __restrict__ xer16, u16* __restrict__ xei16)
{
  __shared__ u16 sA[128*LDT];
  __shared__ u16 sB[128*LDT];
  const int tid = threadIdx.x;
  const int lane = tid & 63, w = tid >> 6;
  const int wr = w >> 1, wc = w & 1;
  const int l15 = lane & 15, l4 = lane >> 4;
  const int m0 = blockIdx.x * 128;
  const int n0 = blockIdx.y * 128;
  f32x4 acc[4][4] = {};
  for (int kb = 0; kb < 4; ++kb) {
    #pragma unroll
    for (int i = 0; i < 4; ++i) {
      int chunk = i*256 + tid;
      int row = chunk >> 3, k0 = (chunk & 7) * 8;
      const float* xs = x + (size_t)(m0+row)*D_ + kb*64 + k0;
      float4 f0 = *(const float4*)xs;
      float4 f1 = *(const float4*)(xs + 4);
      int4 va;
      va.x = (int)((unsigned)f2bf(f0.x) | ((unsigned)f2bf(f0.y) << 16));
      va.y = (int)((unsigned)f2bf(f0.z) | ((unsigned)f2bf(f0.w) << 16));
      va.z = (int)((unsigned)f2bf(f1.x) | ((unsigned)f2bf(f1.y) << 16));
      va.w = (int)((unsigned)f2bf(f1.z) | ((unsigned)f2bf(f1.w) << 16));
      int4 vb = *(const int4*)(Bt + (size_t)(n0+row)*D_ + kb*64 + k0);
      *(int4*)&sA[row*LDT + k0] = va;
      *(int4*)&sB[row*LDT + k0] = vb;
    }
    __syncthreads();
    #pragma unroll
    for (int ks = 0; ks < 2; ++ks) {
      bf16x8 af[4], bb[4];
      #pragma unroll
      for (int mf = 0; mf < 4; ++mf)
        af[mf] = *(const bf16x8*)&sA[(wr*64 + mf*16 + l15)*LDT + ks*32 + l4*8];
      #pragma unroll
      for (int nf = 0; nf < 4; ++nf)
        bb[nf] = *(const bf16x8*)&sB[(wc*64 + nf*16 + l15)*LDT + ks*32 + l4*8];
      #pragma unroll
      for (int mf = 0; mf < 4; ++mf)
        #pragma unroll
        for (int nf = 0; nf < 4; ++nf)
          acc[mf][nf] = __builtin_amdgcn_mfma_f32_16x16x32_bf16(
              af[mf], bb[nf], acc[mf][nf], 0, 0, 0);
    }
    __syncthreads();
  }
  #pragma unroll
  for (int mf = 0; mf < 4; ++mf)
    #pragma unroll
    for (int nf = 0; nf < 4; ++nf)
      #pragma unroll
      for (int r = 0; r < 4; ++r) {
        int row = m0 + wr*64 + mf*16 + l4*4 + r;
        int col = n0 + wc*64 + nf*16 + l15;
        float v = acc[mf][nf][r];
        if (col < 256) xer16[(size_t)row*D_ + col] = f2bf(v);
        else           xei16[(size_t)row*D_ + col - 256] = f2bf(-v);
      }
}

__global__ __launch_bounds__(256) void decode_gemm(
    const u16* __restrict__ hre16, const u16* __restrict__ him16,
    const u16* __restrict__ Bt, float* __restrict__ out)
{
  __shared__ u16 sA[128*LDT];
  __shared__ u16 sB[128*LDT];
  const int tid = threadIdx.x;
  const int lane = tid & 63, w = tid >> 6;
  const int wr = w >> 1, wc = w & 1;
  const int l15 = lane & 15, l4 = lane >> 4;
  const int m0 = blockIdx.x * 128;
  const int n0 = blockIdx.y * 128;
  f32x4 acc[4][4] = {};
  for (int kb = 0; kb < 8; ++kb) {
    const u16* aplane = (kb < 4) ? hre16 : him16;
    const int kk = (kb & 3) * 64;
    #pragma unroll
    for (int i = 0; i < 4; ++i) {
      int chunk = i*256 + tid;
      int row = chunk >> 3, k0 = (chunk & 7) * 8;
      int4 va = *(const int4*)(aplane + (size_t)(m0+row)*D_ + kk + k0);
      int4 vb = *(const int4*)(Bt + (size_t)(n0+row)*512 + kb*64 + k0);
      *(int4*)&sA[row*LDT + k0] = va;
      *(int4*)&sB[row*LDT + k0] = vb;
    }
    __syncthreads();
    #pragma unroll
    for (int ks = 0; ks < 2; ++ks) {
      bf16x8 af[4], bb[4];
      #pragma unroll
      for (int mf = 0; mf < 4; ++mf)
        af[mf] = *(const bf16x8*)&sA[(wr*64 + mf*16 + l15)*LDT + ks*32 + l4*8];
      #pragma unroll
      for (int nf = 0; nf < 4; ++nf)
        bb[nf] = *(const bf16x8*)&sB[(wc*64 + nf*16 + l15)*LDT + ks*32 + l4*8];
      #pragma unroll
      for (int mf = 0; mf < 4; ++mf)
        #pragma unroll
        for (int nf = 0; nf < 4; ++nf)
          acc[mf][nf] = __builtin_amdgcn_mfma_f32_16x16x32_bf16(
              af[mf], bb[nf], acc[mf][nf], 0, 0, 0);
    }
    __syncthreads();
  }
  #pragma unroll
  for (int mf = 0; mf < 4; ++mf)
    #pragma unroll
    for (int nf = 0; nf < 4; ++nf)
      #pragma unroll
      for (int r = 0; r < 4; ++r) {
        int row = m0 + wr*64 + mf*16 + l4*4 + r;
        int col = n0 + wc*64 + nf*16 + l15;
        float v = acc[mf][nf][r];
        if (col < 256) out[(size_t)row*D_ + col] = v;
        else           out[PLANE + (size_t)row*D_ + col - 256] = v;
      }
}

// ---------------------------------------------------------------------------
// Scan with fused coefficient computation (round-4 verified structure).
// One block per (b,n); thread = d; per-t transcendentals hidden under HBM.
// ---------------------------------------------------------------------------
__global__ __launch_bounds__(256) void scan_kernel(
  const float* __restrict__ eps, const float* __restrict__ dt,
  const float* __restrict__ lam_re, const float* __restrict__ lam_im,
  const float* __restrict__ noise_raw,
  const u16* __restrict__ xer16, const u16* __restrict__ xei16,
  u16* __restrict__ hre16, u16* __restrict__ him16)
{
  int bx = blockIdx.x;
  int b = bx >> 9, n = bx & 511;
  int d = threadIdx.x;
  __shared__ float sdt[T_];
  if (d < T_) sdt[d] = dt[b*T_ + d];
  __syncthreads();

  float lr = lam_re[d], li = lam_im[d];
  float lam_r = fmaxf(-log1pf(expf(-lr)), -0.3f);     // -softplus(-x), clamp
  float t0 = lam_r + 1e-12f;
  float sgn = (t0 > 0.f) ? 1.f : ((t0 < 0.f) ? -1.f : 0.f);
  float den_re = lam_r + 1e-8f*sgn, den_im = li;      // lam_safe
  float d2 = den_re*den_re + den_im*den_im;
  float nsc = log1pf(expf(noise_raw[d])) * 0.01f;

  float hr = 0.f, hi = 0.f;
  for (int t = 0; t < T_; ++t) {
    float dtv = sdt[t];
    float er = expf(dtv*lam_r);
    float ai = dtv*li;
    float dre = er*cosf(ai), dim_ = er*sinf(ai);
    float nr = dre - 1.f, ni = dim_;
    float fre = (nr*den_re + ni*den_im)/d2;
    float fim = (ni*den_re - nr*den_im)/d2;
    float ns = sqrtf(fmaxf(dtv, 0.f)) * nsc;
    size_t idx = ((size_t)(b*T_ + t)*N_ + n)*D_ + d;
    float xr = bf2f(xer16[idx]), xi = bf2f(xei16[idx]), ep = eps[idx];
    float br = fre*xr - fim*xi + ep*ns;
    float bi = fre*xi + fim*xr;
    float nr2 = dre*hr - dim_*hi + br;
    float ni2 = dre*hi + dim_*hr + bi;
    hr = nr2; hi = ni2;
    hre16[idx] = f2bf(hr); him16[idx] = f2bf(hi);
  }
}

// ---------------------------------------------------------------------------
extern "C" void kernel_launch(void* const* d_in, const int* in_sizes, int n_in,
                              void* d_out, int out_size, void* d_ws, size_t ws_size,
                              hipStream_t stream)
{
  const float* x         = (const float*)d_in[0];
  const float* dt        = (const float*)d_in[1];
  const float* eps       = (const float*)d_in[2];
  const float* ure_raw   = (const float*)d_in[3];
  const float* uim_raw   = (const float*)d_in[4];
  const float* lam_re    = (const float*)d_in[5];
  const float* lam_im    = (const float*)d_in[6];
  const float* noise_raw = (const float*)d_in[7];
  float* out = (float*)d_out;

  // ws layout (132 MB total):
  //   0       A float2[65536]            512 KB
  //   512K    tau float2[256]
  //   1M      Benc bf16 [512][256]       256 KB
  //   1.5M    Bdec bf16 [512][512]       512 KB
  //   4M      hre16 bf16 [M][256] 32 MB
  //   36M     xer16 32 MB
  //   68M     xei16 32 MB
  //   100M    him16 32 MB
  char* ws = (char*)d_ws;
  float2* A    = (float2*)(ws);
  float2* tau  = (float2*)(ws + 524288);
  u16* Benc    = (u16*)(ws + (1<<20));
  u16* Bdec    = (u16*)(ws + 1572864);
  u16* hre16   = (u16*)(ws + ((size_t)4<<20));
  u16* xer16   = (u16*)(ws + ((size_t)36<<20));
  u16* xei16   = (u16*)(ws + ((size_t)68<<20));
  u16* him16   = (u16*)(ws + ((size_t)100<<20));

  for (int p = 0; p < 8; ++p) {
    int nb = (p == 0) ? 8 : (8 - p);
    qr_megastep<<<nb, 256, 0, stream>>>(ure_raw, uim_raw, A, tau, p);
  }
  qr_bwd_kernel<<<64, 256, 0, stream>>>(A, tau, Benc, Bdec);
  encode_gemm<<<dim3(M_/128, 4), 256, 0, stream>>>(x, Benc, xer16, xei16);
  scan_kernel<<<B_*N_, 256, 0, stream>>>(eps, dt, lam_re, lam_im, noise_raw,
                                         xer16, xei16, hre16, him16);
  decode_gemm<<<dim3(M_/128, 4), 256, 0, stream>>>(hre16, him16, Bdec, out);
}

// Round 9
// 1184.930 us; speedup vs baseline: 2.1714x; 1.2212x over previous
//
#include <hip/hip_runtime.h>
#include <math.h>

// Problem constants (B,T,N,D) = (2,64,512,256)
#define B_ 2
#define T_ 64
#define N_ 512
#define D_ 256
#define M_ (B_*T_*N_)            // 65536 rows for the GEMMs
#define PLANE ((size_t)M_*D_)    // 16777216 elements per output plane

typedef unsigned short u16;
typedef __attribute__((ext_vector_type(8))) short bf16x8;
typedef __attribute__((ext_vector_type(4))) float f32x4;

__device__ __forceinline__ u16 f2bf(float f) {
  union { float f; unsigned u; } cv; cv.f = f;
  unsigned u = cv.u;
  return (u16)((u + 0x7FFFu + ((u >> 16) & 1u)) >> 16);   // RNE
}
__device__ __forceinline__ float bf2f(u16 h) {
  union { unsigned u; float f; } cv; cv.u = ((unsigned)h) << 16;
  return cv.f;
}

// ---------------------------------------------------------------------------
// 64-lane sum via DPP (VALU-only, ~30cy vs ~500+ for ds_swizzle chains).
// row_shr 1/2/4/8 -> lane15/31/47/63 hold row totals; row_bcast:15 (rows 1,3)
// -> lane31=sum(0-31), lane63=sum(32-63); row_bcast:31 (rows 2,3) -> lane63 =
// total. readlane 63 returns wave-uniform sum. bound_ctrl=true: invalid
// sources read 0; masked rows keep old(=0) -> x+=0. All adds exact-order
// deterministic.
// ---------------------------------------------------------------------------
__device__ __forceinline__ float wredsum(float x) {
  x += __uint_as_float(__builtin_amdgcn_update_dpp(0u, __float_as_uint(x), 0x111, 0xf, 0xf, true));
  x += __uint_as_float(__builtin_amdgcn_update_dpp(0u, __float_as_uint(x), 0x112, 0xf, 0xf, true));
  x += __uint_as_float(__builtin_amdgcn_update_dpp(0u, __float_as_uint(x), 0x114, 0xf, 0xf, true));
  x += __uint_as_float(__builtin_amdgcn_update_dpp(0u, __float_as_uint(x), 0x118, 0xf, 0xf, true));
  x += __uint_as_float(__builtin_amdgcn_update_dpp(0u, __float_as_uint(x), 0x142, 0xa, 0xf, true));
  x += __uint_as_float(__builtin_amdgcn_update_dpp(0u, __float_as_uint(x), 0x143, 0xc, 0xf, true));
  return __uint_as_float(__builtin_amdgcn_readlane(__float_as_uint(x), 63));
}
__device__ __forceinline__ float lanebcast(float x, int l) {  // l wave-uniform
  return __uint_as_float(__builtin_amdgcn_readlane(__float_as_uint(x), l));
}

// ---------------------------------------------------------------------------
// Megastep p: ONE launch = [apply V_{p-1} to all trailing panels, in parallel
// across blocks] + [factorize panel p in block 0].
//   role 0:   (p>0: apply V_{p-1} to panel p's 32 cols), factorize panel p.
//   role r>0: p==0: transpose-init panel r cols from raw.
//             p>0 : apply V_{p-1} to panel (p+r) cols.
// Register window for role 0 starts at j0_prev with pivot offset piv=32, so
// all register indices are compile-time (rule #20). Pivot column flows
// through LDS snext. All reduces are DPP (wredsum).
// ---------------------------------------------------------------------------
__global__ __launch_bounds__(256, 1) void qr_megastep(
    const float* __restrict__ ure_raw, const float* __restrict__ uim_raw,
    float2* __restrict__ A, float2* __restrict__ tau, int p)
{
  const int tid = threadIdx.x, lane = tid & 63, w = tid >> 6;
  const int role = blockIdx.x;
  __shared__ float2 sv32[32][256];
  __shared__ float2 stau32[32];
  __shared__ float2 snext[2][256];

  if (p == 0 && role > 0) {
    // transpose-init panel `role`: A[c][r] = raw[r][c]; coalesced raw reads
    const int c0 = 32*role;
    const int c = tid & 31, r0 = tid >> 5;
    for (int r8 = 0; r8 < 32; ++r8) {
      int r = r0 + r8*8;
      A[(size_t)(c0+c)*D_ + r] = make_float2(ure_raw[(size_t)r*D_ + c0 + c],
                                             uim_raw[(size_t)r*D_ + c0 + c]);
    }
    return;
  }

  const int j0p  = 32*(p - 1);          // prev-panel start (valid p>=1)
  const int Rp   = 256 - j0p;
  const int MCHp = (Rp + 63) >> 6;

  if (role > 0) {
    // ===== apply V_{p-1} to panel (p+role) =====
    for (int c = 0; c < 32; ++c) {
      float2 val = make_float2(0.f, 0.f);
      if (tid < Rp) val = A[(size_t)(j0p+c)*D_ + j0p + tid];
      sv32[c][tid] = val;
    }
    if (tid < 32) stau32[tid] = tau[j0p + tid];
    const int c0 = 32*(p + role);
    float2 col[8][4];
    #pragma unroll
    for (int lc = 0; lc < 8; ++lc) {
      int cg = c0 + lc*4 + w;
      #pragma unroll
      for (int m = 0; m < 4; ++m) {
        int rr = m*64 + lane;
        col[lc][m] = make_float2(0.f, 0.f);
        if (m < MCHp && rr < Rp) col[lc][m] = A[(size_t)cg*D_ + j0p + rr];
      }
    }
    __syncthreads();
    #pragma unroll 1
    for (int jl = 0; jl < 32; ++jl) {
      float2 tt = stau32[jl];
      float2 v[4];
      { float2 rv = sv32[jl][lane];
        v[0] = (lane > jl) ? rv : ((lane == jl) ? make_float2(1.f, 0.f)
                                                : make_float2(0.f, 0.f)); }
      #pragma unroll
      for (int m = 1; m < 4; ++m) v[m] = sv32[jl][m*64 + lane];
      float wr[8], wi[8];
      #pragma unroll
      for (int lc = 0; lc < 8; ++lc) {
        wr[lc] = 0.f; wi[lc] = 0.f;
        #pragma unroll
        for (int m = 0; m < 4; ++m) {
          if (m < MCHp) {
            float2 a = col[lc][m];
            wr[lc] += v[m].x*a.x + v[m].y*a.y;
            wi[lc] += v[m].x*a.y - v[m].y*a.x;
          }
        }
      }
      #pragma unroll
      for (int lc = 0; lc < 8; ++lc) { wr[lc] = wredsum(wr[lc]);
                                       wi[lc] = wredsum(wi[lc]); }
      #pragma unroll
      for (int lc = 0; lc < 8; ++lc) {
        float fr = tt.x*wr[lc] + tt.y*wi[lc];          // f = conj(tau)*w
        float fi = tt.x*wi[lc] - tt.y*wr[lc];
        #pragma unroll
        for (int m = 0; m < 4; ++m) {
          if (m < MCHp) {
            col[lc][m].x -= fr*v[m].x - fi*v[m].y;
            col[lc][m].y -= fr*v[m].y + fi*v[m].x;
          }
        }
      }
    }
    #pragma unroll
    for (int lc = 0; lc < 8; ++lc) {
      int cg = c0 + lc*4 + w;
      #pragma unroll
      for (int m = 0; m < 4; ++m) {
        int rr = m*64 + lane;
        if (m < MCHp && rr < Rp) A[(size_t)cg*D_ + j0p + rr] = col[lc][m];
      }
    }
    return;
  }

  // ===== role 0: panel p =====
  const int piv  = (p == 0) ? 0 : 32;       // pivot offset inside window
  const int j0w  = (p == 0) ? 0 : j0p;      // register window start row
  const int Rw   = 256 - j0w;
  const int MCHw = (Rw + 63) >> 6;

  float2 col[8][4];
  if (p == 0) {
    #pragma unroll
    for (int lc = 0; lc < 8; ++lc) {
      int cg = lc*4 + w;
      #pragma unroll
      for (int m = 0; m < 4; ++m) {
        int rr = m*64 + lane;
        col[lc][m] = make_float2(ure_raw[(size_t)rr*D_ + cg],
                                 uim_raw[(size_t)rr*D_ + cg]);
      }
    }
  } else {
    for (int c = 0; c < 32; ++c) {
      float2 val = make_float2(0.f, 0.f);
      if (tid < Rp) val = A[(size_t)(j0p+c)*D_ + j0p + tid];
      sv32[c][tid] = val;
    }
    if (tid < 32) stau32[tid] = tau[j0p + tid];
    #pragma unroll
    for (int lc = 0; lc < 8; ++lc) {
      int cg = 32*p + lc*4 + w;
      #pragma unroll
      for (int m = 0; m < 4; ++m) {
        int rr = m*64 + lane;
        col[lc][m] = make_float2(0.f, 0.f);
        if (m < MCHp && rr < Rp) col[lc][m] = A[(size_t)cg*D_ + j0p + rr];
      }
    }
    __syncthreads();
    // apply V_{p-1} to own 32 columns
    #pragma unroll 1
    for (int jl = 0; jl < 32; ++jl) {
      float2 tt = stau32[jl];
      float2 v[4];
      { float2 rv = sv32[jl][lane];
        v[0] = (lane > jl) ? rv : ((lane == jl) ? make_float2(1.f, 0.f)
                                                : make_float2(0.f, 0.f)); }
      #pragma unroll
      for (int m = 1; m < 4; ++m) v[m] = sv32[jl][m*64 + lane];
      float wr[8], wi[8];
      #pragma unroll
      for (int lc = 0; lc < 8; ++lc) {
        wr[lc] = 0.f; wi[lc] = 0.f;
        #pragma unroll
        for (int m = 0; m < 4; ++m) {
          if (m < MCHp) {
            float2 a = col[lc][m];
            wr[lc] += v[m].x*a.x + v[m].y*a.y;
            wi[lc] += v[m].x*a.y - v[m].y*a.x;
          }
        }
      }
      #pragma unroll
      for (int lc = 0; lc < 8; ++lc) { wr[lc] = wredsum(wr[lc]);
                                       wi[lc] = wredsum(wi[lc]); }
      #pragma unroll
      for (int lc = 0; lc < 8; ++lc) {
        float fr = tt.x*wr[lc] + tt.y*wi[lc];
        float fi = tt.x*wi[lc] - tt.y*wr[lc];
        #pragma unroll
        for (int m = 0; m < 4; ++m) {
          if (m < MCHp) {
            col[lc][m].x -= fr*v[m].x - fi*v[m].y;
            col[lc][m].y -= fr*v[m].y + fi*v[m].x;
          }
        }
      }
    }
  }

  if (w == 0) {
    #pragma unroll
    for (int m = 0; m < 4; ++m) snext[0][m*64 + lane] = col[0][m];
  }
  __syncthreads();

  // factorize 32 reflectors; pivot row = piv + jl (always in chunk 0)
  #pragma unroll 1
  for (int jl = 0; jl < 32; ++jl) {
    const int cur = jl & 1, nxt = cur ^ 1;
    float2 pc[4];
    #pragma unroll
    for (int m = 0; m < 4; ++m) pc[m] = snext[cur][m*64 + lane];
    float part = (lane > piv + jl) ? (pc[0].x*pc[0].x + pc[0].y*pc[0].y) : 0.f;
    if (1 < MCHw) part += pc[1].x*pc[1].x + pc[1].y*pc[1].y;
    if (2 < MCHw) part += pc[2].x*pc[2].x + pc[2].y*pc[2].y;
    if (3 < MCHw) part += pc[3].x*pc[3].x + pc[3].y*pc[3].y;
    part = wredsum(part);
    float ar = lanebcast(pc[0].x, piv + jl), ai = lanebcast(pc[0].y, piv + jl);
    float taur, taui, sclr, scli, beta;
    if (part == 0.f && ai == 0.f) {
      taur = taui = sclr = scli = 0.f; beta = ar;      // H = I
    } else {
      float nrm = sqrtf(ar*ar + ai*ai + part);
      beta = (ar >= 0.f) ? -nrm : nrm;                 // -SIGN(nrm, Re(alpha))
      taur = (beta - ar)/beta; taui = -ai/beta;
      float dr = ar - beta, di = ai, dn = dr*dr + di*di;
      sclr = dr/dn; scli = -di/dn;                     // 1/(alpha-beta)
    }
    if (w == 3 && lane == 0) tau[32*p + jl] = make_float2(taur, taui);
    float2 v[4];
    {
      float2 t0 = make_float2(pc[0].x*sclr - pc[0].y*scli,
                              pc[0].x*scli + pc[0].y*sclr);
      v[0] = (lane > piv + jl) ? t0 : ((lane == piv + jl)
                 ? make_float2(1.f, 0.f) : make_float2(0.f, 0.f));
    }
    #pragma unroll
    for (int m = 1; m < 4; ++m)
      v[m] = make_float2(pc[m].x*sclr - pc[m].y*scli,
                         pc[m].x*scli + pc[m].y*sclr);
    if (w == 3) {
      #pragma unroll
      for (int m = 0; m < 4; ++m) {
        int rr = m*64 + lane;
        float2 o = v[m];
        if (m == 0) {
          if (lane < piv + jl)       o = pc[0];
          else if (lane == piv + jl) o = make_float2(beta, 0.f);
        }
        if (m < MCHw && rr < Rw) A[(size_t)(32*p + jl)*D_ + j0w + rr] = o;
      }
    }
    #pragma unroll
    for (int lc = 0; lc < 8; ++lc) {
      int cl = lc*4 + w;
      if (cl > jl) {
        float wr, wi;
        { float2 a = col[lc][0];
          wr = v[0].x*a.x + v[0].y*a.y; wi = v[0].x*a.y - v[0].y*a.x; }
        if (1 < MCHw) { float2 a = col[lc][1];
          wr += v[1].x*a.x + v[1].y*a.y; wi += v[1].x*a.y - v[1].y*a.x; }
        if (2 < MCHw) { float2 a = col[lc][2];
          wr += v[2].x*a.x + v[2].y*a.y; wi += v[2].x*a.y - v[2].y*a.x; }
        if (3 < MCHw) { float2 a = col[lc][3];
          wr += v[3].x*a.x + v[3].y*a.y; wi += v[3].x*a.y - v[3].y*a.x; }
        wr = wredsum(wr); wi = wredsum(wi);
        float fr = taur*wr + taui*wi;                  // f = conj(tau)*w
        float fi = taur*wi - taui*wr;
        { col[lc][0].x -= fr*v[0].x - fi*v[0].y;
          col[lc][0].y -= fr*v[0].y + fi*v[0].x; }
        if (1 < MCHw) { col[lc][1].x -= fr*v[1].x - fi*v[1].y;
                        col[lc][1].y -= fr*v[1].y + fi*v[1].x; }
        if (2 < MCHw) { col[lc][2].x -= fr*v[2].x - fi*v[2].y;
                        col[lc][2].y -= fr*v[2].y + fi*v[2].x; }
        if (3 < MCHw) { col[lc][3].x -= fr*v[3].x - fi*v[3].y;
                        col[lc][3].y -= fr*v[3].y + fi*v[3].x; }
        if (cl == jl + 1) {
          #pragma unroll
          for (int m = 0; m < 4; ++m) snext[nxt][m*64 + lane] = col[lc][m];
        }
      }
    }
    __syncthreads();
  }
}

// ---------------------------------------------------------------------------
// zung2r: column c of Q = H_0(...H_c(e_c)); one wave per column; depth-2
// register prefetch; DPP reduce. Epilogue writes bf16 B^T matrices.
// ---------------------------------------------------------------------------
__global__ __launch_bounds__(256, 1) void qr_bwd_kernel(
    const float2* __restrict__ A, const float2* __restrict__ tau,
    u16* __restrict__ Benc, u16* __restrict__ Bdec)
{
  const int lane = threadIdx.x & 63;
  const int w = threadIdx.x >> 6;
  const int c = blockIdx.x * 4 + w;          // column 0..255
  __shared__ float2 stau[256];
  if (threadIdx.x < 256) stau[threadIdx.x] = tau[threadIdx.x];
  __syncthreads();

  float2 q[4];
  #pragma unroll
  for (int m = 0; m < 4; ++m) {
    q[m] = make_float2(0.f, 0.f);
    if (m*64 + lane == c) q[m].x = 1.f;      // q = e_c
  }
  float2 a0[4], a1[4];
  #pragma unroll
  for (int m = 0; m < 4; ++m) a0[m] = A[(size_t)c*D_ + m*64 + lane];
  {
    int i1 = (c >= 1) ? c - 1 : 0;
    #pragma unroll
    for (int m = 0; m < 4; ++m) a1[m] = A[(size_t)i1*D_ + m*64 + lane];
  }

  #pragma unroll 1
  for (int i = c; i >= 0; --i) {
    int ip = (i >= 2) ? i - 2 : 0;
    float2 a2[4];
    #pragma unroll
    for (int m = 0; m < 4; ++m) a2[m] = A[(size_t)ip*D_ + m*64 + lane];

    float2 tt = stau[i];
    float2 v[4];
    #pragma unroll
    for (int m = 0; m < 4; ++m) {
      int r = m*64 + lane;
      v[m] = (r > i) ? a0[m] : ((r == i) ? make_float2(1.f, 0.f)
                                         : make_float2(0.f, 0.f));
    }
    float wr = 0.f, wi = 0.f;
    #pragma unroll
    for (int m = 0; m < 4; ++m) {
      wr += v[m].x*q[m].x + v[m].y*q[m].y;   // w += conj(v)*q
      wi += v[m].x*q[m].y - v[m].y*q[m].x;
    }
    wr = wredsum(wr); wi = wredsum(wi);
    float fr = tt.x*wr - tt.y*wi;            // f = tau*w (0 when tau==0)
    float fi = tt.x*wi + tt.y*wr;
    #pragma unroll
    for (int m = 0; m < 4; ++m) {
      q[m].x -= fr*v[m].x - fi*v[m].y;
      q[m].y -= fr*v[m].y + fi*v[m].x;
      a0[m] = a1[m]; a1[m] = a2[m];
    }
  }

  #pragma unroll
  for (int m = 0; m < 4; ++m) {
    int r = m*64 + lane;
    u16 qre = f2bf(q[m].x), qim = f2bf(q[m].y), qimn = f2bf(-q[m].y);
    Benc[(size_t)c*D_ + r]              = qre;
    Benc[(size_t)(c+256)*D_ + r]        = qim;
    Bdec[(size_t)c*512 + r]             = qre;
    Bdec[(size_t)c*512 + 256 + r]       = qimn;
    Bdec[(size_t)(c+256)*512 + r]       = qim;
    Bdec[(size_t)(c+256)*512 + 256 + r] = qre;
  }
}

// ---------------------------------------------------------------------------
// bf16 MFMA GEMM, 128x128 tile, 4 waves, BK=64, 16x16x32 MFMA.
// encode_gemm reads fp32 x directly and converts during staging.
// LDS row stride 72 elements (144 B): 16B-aligned, 2-way banks (free).
// ---------------------------------------------------------------------------
#define LDT 72

__global__ __launch_bounds__(256) void encode_gemm(
    const float* __restrict__ x, const u16* __restrict__ Bt,
    u16* __restrict__ xer16, u16* __restrict__ xei16)
{
  __shared__ u16 sA[128*LDT];
  __shared__ u16 sB[128*LDT];
  const int tid = threadIdx.x;
  const int lane = tid & 63, w = tid >> 6;
  const int wr = w >> 1, wc = w & 1;
  const int l15 = lane & 15, l4 = lane >> 4;
  const int m0 = blockIdx.x * 128;
  const int n0 = blockIdx.y * 128;
  f32x4 acc[4][4] = {};
  for (int kb = 0; kb < 4; ++kb) {
    #pragma unroll
    for (int i = 0; i < 4; ++i) {
      int chunk = i*256 + tid;
      int row = chunk >> 3, k0 = (chunk & 7) * 8;
      const float* xs = x + (size_t)(m0+row)*D_ + kb*64 + k0;
      float4 f0 = *(const float4*)xs;
      float4 f1 = *(const float4*)(xs + 4);
      int4 va;
      va.x = (int)((unsigned)f2bf(f0.x) | ((unsigned)f2bf(f0.y) << 16));
      va.y = (int)((unsigned)f2bf(f0.z) | ((unsigned)f2bf(f0.w) << 16));
      va.z = (int)((unsigned)f2bf(f1.x) | ((unsigned)f2bf(f1.y) << 16));
      va.w = (int)((unsigned)f2bf(f1.z) | ((unsigned)f2bf(f1.w) << 16));
      int4 vb = *(const int4*)(Bt + (size_t)(n0+row)*D_ + kb*64 + k0);
      *(int4*)&sA[row*LDT + k0] = va;
      *(int4*)&sB[row*LDT + k0] = vb;
    }
    __syncthreads();
    #pragma unroll
    for (int ks = 0; ks < 2; ++ks) {
      bf16x8 af[4], bb[4];
      #pragma unroll
      for (int mf = 0; mf < 4; ++mf)
        af[mf] = *(const bf16x8*)&sA[(wr*64 + mf*16 + l15)*LDT + ks*32 + l4*8];
      #pragma unroll
      for (int nf = 0; nf < 4; ++nf)
        bb[nf] = *(const bf16x8*)&sB[(wc*64 + nf*16 + l15)*LDT + ks*32 + l4*8];
      #pragma unroll
      for (int mf = 0; mf < 4; ++mf)
        #pragma unroll
        for (int nf = 0; nf < 4; ++nf)
          acc[mf][nf] = __builtin_amdgcn_mfma_f32_16x16x32_bf16(
              af[mf], bb[nf], acc[mf][nf], 0, 0, 0);
    }
    __syncthreads();
  }
  #pragma unroll
  for (int mf = 0; mf < 4; ++mf)
    #pragma unroll
    for (int nf = 0; nf < 4; ++nf)
      #pragma unroll
      for (int r = 0; r < 4; ++r) {
        int row = m0 + wr*64 + mf*16 + l4*4 + r;
        int col = n0 + wc*64 + nf*16 + l15;
        float v = acc[mf][nf][r];
        if (col < 256) xer16[(size_t)row*D_ + col] = f2bf(v);
        else           xei16[(size_t)row*D_ + col - 256] = f2bf(-v);
      }
}

__global__ __launch_bounds__(256) void decode_gemm(
    const u16* __restrict__ hre16, const u16* __restrict__ him16,
    const u16* __restrict__ Bt, float* __restrict__ out)
{
  __shared__ u16 sA[128*LDT];
  __shared__ u16 sB[128*LDT];
  const int tid = threadIdx.x;
  const int lane = tid & 63, w = tid >> 6;
  const int wr = w >> 1, wc = w & 1;
  const int l15 = lane & 15, l4 = lane >> 4;
  const int m0 = blockIdx.x * 128;
  const int n0 = blockIdx.y * 128;
  f32x4 acc[4][4] = {};
  for (int kb = 0; kb < 8; ++kb) {
    const u16* aplane = (kb < 4) ? hre16 : him16;
    const int kk = (kb & 3) * 64;
    #pragma unroll
    for (int i = 0; i < 4; ++i) {
      int chunk = i*256 + tid;
      int row = chunk >> 3, k0 = (chunk & 7) * 8;
      int4 va = *(const int4*)(aplane + (size_t)(m0+row)*D_ + kk + k0);
      int4 vb = *(const int4*)(Bt + (size_t)(n0+row)*512 + kb*64 + k0);
      *(int4*)&sA[row*LDT + k0] = va;
      *(int4*)&sB[row*LDT + k0] = vb;
    }
    __syncthreads();
    #pragma unroll
    for (int ks = 0; ks < 2; ++ks) {
      bf16x8 af[4], bb[4];
      #pragma unroll
      for (int mf = 0; mf < 4; ++mf)
        af[mf] = *(const bf16x8*)&sA[(wr*64 + mf*16 + l15)*LDT + ks*32 + l4*8];
      #pragma unroll
      for (int nf = 0; nf < 4; ++nf)
        bb[nf] = *(const bf16x8*)&sB[(wc*64 + nf*16 + l15)*LDT + ks*32 + l4*8];
      #pragma unroll
      for (int mf = 0; mf < 4; ++mf)
        #pragma unroll
        for (int nf = 0; nf < 4; ++nf)
          acc[mf][nf] = __builtin_amdgcn_mfma_f32_16x16x32_bf16(
              af[mf], bb[nf], acc[mf][nf], 0, 0, 0);
    }
    __syncthreads();
  }
  #pragma unroll
  for (int mf = 0; mf < 4; ++mf)
    #pragma unroll
    for (int nf = 0; nf < 4; ++nf)
      #pragma unroll
      for (int r = 0; r < 4; ++r) {
        int row = m0 + wr*64 + mf*16 + l4*4 + r;
        int col = n0 + wc*64 + nf*16 + l15;
        float v = acc[mf][nf][r];
        if (col < 256) out[(size_t)row*D_ + col] = v;
        else           out[PLANE + (size_t)row*D_ + col - 256] = v;
      }
}

// ---------------------------------------------------------------------------
// Scan with fused coefficient computation. One block per (b,n); thread = d.
// ---------------------------------------------------------------------------
__global__ __launch_bounds__(256) void scan_kernel(
  const float* __restrict__ eps, const float* __restrict__ dt,
  const float* __restrict__ lam_re, const float* __restrict__ lam_im,
  const float* __restrict__ noise_raw,
  const u16* __restrict__ xer16, const u16* __restrict__ xei16,
  u16* __restrict__ hre16, u16* __restrict__ him16)
{
  int bx = blockIdx.x;
  int b = bx >> 9, n = bx & 511;
  int d = threadIdx.x;
  __shared__ float sdt[T_];
  if (d < T_) sdt[d] = dt[b*T_ + d];
  __syncthreads();

  float lr = lam_re[d], li = lam_im[d];
  float lam_r = fmaxf(-log1pf(expf(-lr)), -0.3f);     // -softplus(-x), clamp
  float t0 = lam_r + 1e-12f;
  float sgn = (t0 > 0.f) ? 1.f : ((t0 < 0.f) ? -1.f : 0.f);
  float den_re = lam_r + 1e-8f*sgn, den_im = li;      // lam_safe
  float d2 = den_re*den_re + den_im*den_im;
  float nsc = log1pf(expf(noise_raw[d])) * 0.01f;

  float hr = 0.f, hi = 0.f;
  for (int t = 0; t < T_; ++t) {
    float dtv = sdt[t];
    float er = expf(dtv*lam_r);
    float ai = dtv*li;
    float dre = er*cosf(ai), dim_ = er*sinf(ai);
    float nr = dre - 1.f, ni = dim_;
    float fre = (nr*den_re + ni*den_im)/d2;
    float fim = (ni*den_re - nr*den_im)/d2;
    float ns = sqrtf(fmaxf(dtv, 0.f)) * nsc;
    size_t idx = ((size_t)(b*T_ + t)*N_ + n)*D_ + d;
    float xr = bf2f(xer16[idx]), xi = bf2f(xei16[idx]), ep = eps[idx];
    float br = fre*xr - fim*xi + ep*ns;
    float bi = fre*xi + fim*xr;
    float nr2 = dre*hr - dim_*hi + br;
    float ni2 = dre*hi + dim_*hr + bi;
    hr = nr2; hi = ni2;
    hre16[idx] = f2bf(hr); him16[idx] = f2bf(hi);
  }
}

// ---------------------------------------------------------------------------
extern "C" void kernel_launch(void* const* d_in, const int* in_sizes, int n_in,
                              void* d_out, int out_size, void* d_ws, size_t ws_size,
                              hipStream_t stream)
{
  const float* x         = (const float*)d_in[0];
  const float* dt        = (const float*)d_in[1];
  const float* eps       = (const float*)d_in[2];
  const float* ure_raw   = (const float*)d_in[3];
  const float* uim_raw   = (const float*)d_in[4];
  const float* lam_re    = (const float*)d_in[5];
  const float* lam_im    = (const float*)d_in[6];
  const float* noise_raw = (const float*)d_in[7];
  float* out = (float*)d_out;

  // ws layout (132 MB total):
  //   0       A float2[65536]            512 KB
  //   512K    tau float2[256]
  //   1M      Benc bf16 [512][256]       256 KB
  //   1.5M    Bdec bf16 [512][512]       512 KB
  //   4M      hre16 bf16 [M][256] 32 MB
  //   36M     xer16 32 MB
  //   68M     xei16 32 MB
  //   100M    him16 32 MB
  char* ws = (char*)d_ws;
  float2* A    = (float2*)(ws);
  float2* tau  = (float2*)(ws + 524288);
  u16* Benc    = (u16*)(ws + (1<<20));
  u16* Bdec    = (u16*)(ws + 1572864);
  u16* hre16   = (u16*)(ws + ((size_t)4<<20));
  u16* xer16   = (u16*)(ws + ((size_t)36<<20));
  u16* xei16   = (u16*)(ws + ((size_t)68<<20));
  u16* him16   = (u16*)(ws + ((size_t)100<<20));

  for (int p = 0; p < 8; ++p) {
    int nb = (p == 0) ? 8 : (8 - p);
    qr_megastep<<<nb, 256, 0, stream>>>(ure_raw, uim_raw, A, tau, p);
  }
  qr_bwd_kernel<<<64, 256, 0, stream>>>(A, tau, Benc, Bdec);
  encode_gemm<<<dim3(M_/128, 4), 256, 0, stream>>>(x, Benc, xer16, xei16);
  scan_kernel<<<B_*N_, 256, 0, stream>>>(eps, dt, lam_re, lam_im, noise_raw,
                                         xer16, xei16, hre16, him16);
  decode_gemm<<<dim3(M_/128, 4), 256, 0, stream>>>(hre16, him16, Bdec, out);
}